// Round 2
// baseline (2179.170 us; speedup 1.0000x reference)
//
#include <hip/hip_runtime.h>
#include <hip/hip_bf16.h>
#include <math.h>

#define N_NODES 8192
#define DIN 384
#define DH 512
#define KNB 6
#define NEG_SLOPE 0.01f

// ---------------------------------------------------------------------------
// Generic 64x64-tile fp32 GEMM: C = act(A[MxK] @ W[KxN] + bias) (+C if ACC)
// block 256 threads, micro-tile 4x4, K-step 32, k-major LDS tiles (b128 reads)
// ---------------------------------------------------------------------------
template <int ACT, int ACC>
__global__ __launch_bounds__(256) void gemm64(const float* __restrict__ A,
                                              const float* __restrict__ W,
                                              const float* __restrict__ bias,
                                              float* __restrict__ C,
                                              int M, int K, int N) {
  __shared__ float sA[32][68];  // [k][row]
  __shared__ float sB[32][68];  // [k][col]
  const int tid = threadIdx.x;
  const int ty = tid >> 4, tx = tid & 15;
  const int row0 = blockIdx.y << 6;
  const int col0 = blockIdx.x << 6;
  float acc[4][4] = {};
  for (int kk = 0; kk < K; kk += 32) {
#pragma unroll
    for (int L = 0; L < 2; ++L) {
      int e = (tid + (L << 8)) << 2;  // 0..2044, step 4
      int r = e >> 5, c = e & 31;
      const float4 a4 = *reinterpret_cast<const float4*>(A + (size_t)(row0 + r) * K + kk + c);
      sA[c + 0][r] = a4.x; sA[c + 1][r] = a4.y; sA[c + 2][r] = a4.z; sA[c + 3][r] = a4.w;
      int kr = e >> 6, cc = e & 63;
      *reinterpret_cast<float4*>(&sB[kr][cc]) =
          *reinterpret_cast<const float4*>(W + (size_t)(kk + kr) * N + col0 + cc);
    }
    __syncthreads();
#pragma unroll
    for (int k = 0; k < 32; ++k) {
      float4 av = *reinterpret_cast<float4*>(&sA[k][ty << 2]);
      float4 bv = *reinterpret_cast<float4*>(&sB[k][tx << 2]);
      float aa[4] = {av.x, av.y, av.z, av.w};
      float bb[4] = {bv.x, bv.y, bv.z, bv.w};
#pragma unroll
      for (int i = 0; i < 4; ++i)
#pragma unroll
        for (int j = 0; j < 4; ++j) acc[i][j] = fmaf(aa[i], bb[j], acc[i][j]);
    }
    __syncthreads();
  }
#pragma unroll
  for (int i = 0; i < 4; ++i) {
    int r = row0 + (ty << 2) + i;
    int c = col0 + (tx << 2);
    float4 o;
    float vals[4];
#pragma unroll
    for (int j = 0; j < 4; ++j) {
      float v = acc[i][j] + bias[c + j];
      if (ACT == 1) v = v > 0.f ? v : NEG_SLOPE * v;
      vals[j] = v;
    }
    o.x = vals[0]; o.y = vals[1]; o.z = vals[2]; o.w = vals[3];
    float4* dst = reinterpret_cast<float4*>(C + (size_t)r * N + c);
    if (ACC) {
      float4 old = *dst;
      o.x += old.x; o.y += old.y; o.z += old.z; o.w += old.w;
    }
    *dst = o;
  }
}

// ---------------------------------------------------------------------------
// Column sums of X[8192 x 512] (for mean over nodes)
// ---------------------------------------------------------------------------
__global__ __launch_bounds__(256) void colsum_kernel(const float* __restrict__ X,
                                                     float* __restrict__ cs) {
  const int tid = threadIdx.x;
  float s0 = 0.f, s1 = 0.f;
  const int r0 = blockIdx.x * 128;
  for (int r = r0; r < r0 + 128; ++r) {
    s0 += X[(size_t)r * DH + tid];
    s1 += X[(size_t)r * DH + tid + 256];
  }
  atomicAdd(&cs[tid], s0);
  atomicAdd(&cs[tid + 256], s1);
}

// x = (x + colmean) * 0.5
__global__ __launch_bounds__(256) void mix_kernel(float* __restrict__ X,
                                                  const float* __restrict__ cs) {
  const int gid = blockIdx.x * 256 + threadIdx.x;  // one float4 each
  const int c4 = (gid & 127) << 2;
  float4 x = *reinterpret_cast<float4*>(X + (size_t)gid * 4);
  const float inv = 1.f / 8192.f;
  x.x = (x.x + cs[c4 + 0] * inv) * 0.5f;
  x.y = (x.y + cs[c4 + 1] * inv) * 0.5f;
  x.z = (x.z + cs[c4 + 2] * inv) * 0.5f;
  x.w = (x.w + cs[c4 + 3] * inv) * 0.5f;
  *reinterpret_cast<float4*>(X + (size_t)gid * 4) = x;
}

// ---------------------------------------------------------------------------
// Fused scoring GEMM + streaming per-row top-6.
// grid (2 j-splits, 128 row-blocks), block 256. Row stripe = 64 rows,
// j half-range = 4096 scanned in 64-col tiles. Private sorted top-6/thread
// (each thread owns a 16-col quarter of one row), merged via LDS at the end.
// ---------------------------------------------------------------------------
__global__ __launch_bounds__(256) void score_topk(const float* __restrict__ EH,
                                                  const float* __restrict__ ET,
                                                  float* __restrict__ tkv,
                                                  int* __restrict__ tki) {
  __shared__ float sA[32][68];
  __shared__ float sB[32][68];
  __shared__ float ssc[64][68];
  const int tid = threadIdx.x;
  const int ty = tid >> 4, tx = tid & 15;
  const int row0 = blockIdx.y << 6;
  const int j0 = blockIdx.x << 12;
  const float scale = 0.044194173824159216f;  // 512^-0.5
  float tv[6];
  int ti[6];
#pragma unroll
  for (int s = 0; s < 6; ++s) { tv[s] = -3.4e38f; ti[s] = -1; }
  const int srow = tid >> 2;
  const int sq = tid & 3;
  for (int jt = 0; jt < 64; ++jt) {
    const int jb = j0 + (jt << 6);
    float acc[4][4] = {};
    for (int kk = 0; kk < DH; kk += 32) {
#pragma unroll
      for (int L = 0; L < 2; ++L) {
        int e = (tid + (L << 8)) << 2;
        int r = e >> 5, c = e & 31;
        const float4 a4 = *reinterpret_cast<const float4*>(EH + (size_t)(row0 + r) * DH + kk + c);
        sA[c + 0][r] = a4.x * scale; sA[c + 1][r] = a4.y * scale;
        sA[c + 2][r] = a4.z * scale; sA[c + 3][r] = a4.w * scale;
        const float4 b4 = *reinterpret_cast<const float4*>(ET + (size_t)(jb + r) * DH + kk + c);
        sB[c + 0][r] = b4.x; sB[c + 1][r] = b4.y; sB[c + 2][r] = b4.z; sB[c + 3][r] = b4.w;
      }
      __syncthreads();
#pragma unroll
      for (int k = 0; k < 32; ++k) {
        float4 av = *reinterpret_cast<float4*>(&sA[k][ty << 2]);
        float4 bv = *reinterpret_cast<float4*>(&sB[k][tx << 2]);
        float aa[4] = {av.x, av.y, av.z, av.w};
        float bb[4] = {bv.x, bv.y, bv.z, bv.w};
#pragma unroll
        for (int i = 0; i < 4; ++i)
#pragma unroll
          for (int j = 0; j < 4; ++j) acc[i][j] = fmaf(aa[i], bb[j], acc[i][j]);
      }
      __syncthreads();
    }
#pragma unroll
    for (int i = 0; i < 4; ++i)
      *reinterpret_cast<float4*>(&ssc[(ty << 2) + i][tx << 2]) =
          make_float4(acc[i][0], acc[i][1], acc[i][2], acc[i][3]);
    __syncthreads();
#pragma unroll
    for (int c = 0; c < 16; ++c) {
      float v = ssc[srow][(sq << 4) + c];
      int idx = jb + (sq << 4) + c;
      if (v > tv[5]) {  // strict > keeps earliest index on ties
        tv[5] = v; ti[5] = idx;
#pragma unroll
        for (int p = 5; p > 0; --p) {
          if (tv[p] > tv[p - 1]) {
            float tvt = tv[p]; tv[p] = tv[p - 1]; tv[p - 1] = tvt;
            int tit = ti[p]; ti[p] = ti[p - 1]; ti[p - 1] = tit;
          }
        }
      }
    }
    __syncthreads();
  }
  // merge the 4 quarter-lists per row
  float* vbuf = &ssc[0][0];                       // 64*4*6 = 1536 floats
  int* ibuf = reinterpret_cast<int*>(&sA[0][0]);  // 1536 ints
#pragma unroll
  for (int s = 0; s < 6; ++s) {
    vbuf[(srow * 4 + sq) * 6 + s] = tv[s];
    ibuf[(srow * 4 + sq) * 6 + s] = ti[s];
  }
  __syncthreads();
  if (sq == 0) {
    int ptr[4] = {0, 0, 0, 0};
    const int gr = row0 + srow;
    const int base = (blockIdx.x * N_NODES + gr) * 6;
    for (int s = 0; s < 6; ++s) {
      float best = -3.4e38f;
      int bi = 0x7fffffff, bq = 0;
#pragma unroll
      for (int q = 0; q < 4; ++q) {
        float v = vbuf[(srow * 4 + q) * 6 + ptr[q]];
        int ix = ibuf[(srow * 4 + q) * 6 + ptr[q]];
        bool take = (ptr[q] < 6) && ((v > best) || (v == best && ix < bi));
        if (take) { best = v; bi = ix; bq = q; }
      }
      tkv[base + s] = best;
      tki[base + s] = bi;
      ptr[bq]++;
    }
  }
}

// merge the two j-split top-6 lists into final top-6
__global__ __launch_bounds__(256) void merge_topk(const float* __restrict__ tkv,
                                                  const int* __restrict__ tki,
                                                  float* __restrict__ fw,
                                                  int* __restrict__ fi) {
  const int n = blockIdx.x * 256 + threadIdx.x;
  const float* v0 = tkv + (size_t)n * 6;
  const int* i0 = tki + (size_t)n * 6;
  const float* v1 = tkv + (size_t)(N_NODES + n) * 6;
  const int* i1 = tki + (size_t)(N_NODES + n) * 6;
  int p0 = 0, p1 = 0;
  for (int s = 0; s < 6; ++s) {
    float a = v0[p0], b = v1[p1];
    int ia = i0[p0], ib = i1[p1];
    bool takeA = (a > b) || (a == b && ia < ib);
    if (takeA) { fw[n * 6 + s] = a; fi[n * 6 + s] = ia; ++p0; }
    else       { fw[n * 6 + s] = b; fi[n * 6 + s] = ib; ++p1; }
  }
}

// ---------------------------------------------------------------------------
// Per-node neighbor aggregation: p-softmax mix, tanh gate, ka-softmax,
// outputs U = e_h + e_Nh, V = e_h * e_Nh.  One block per node.
// ---------------------------------------------------------------------------
__global__ __launch_bounds__(256) void agg_kernel(const float* __restrict__ EH,
                                                  const float* __restrict__ ET,
                                                  const float* __restrict__ fw,
                                                  const int* __restrict__ fi,
                                                  float* __restrict__ U,
                                                  float* __restrict__ V) {
  __shared__ float sNb[KNB][DH];
  __shared__ float sred[4][8];
  __shared__ float ska[8];
  const int node = blockIdx.x;
  const int tid = threadIdx.x;
  float w[KNB];
  int idx[KNB];
#pragma unroll
  for (int k = 0; k < KNB; ++k) {
    w[k] = fw[node * KNB + k];
    idx[k] = fi[node * KNB + k];
  }
  float mx = w[0];
#pragma unroll
  for (int k = 1; k < KNB; ++k) mx = fmaxf(mx, w[k]);
  float pk[KNB];
  float se = 0.f;
#pragma unroll
  for (int k = 0; k < KNB; ++k) { pk[k] = expf(w[k] - mx); se += pk[k]; }
  const float inv_se = 1.f / se;
#pragma unroll
  for (int k = 0; k < KNB; ++k) pk[k] *= inv_se;
  for (int e = tid; e < KNB * DH; e += 256) {
    int k = e >> 9, d = e & 511;
    sNb[k][d] = ET[(size_t)idx[k] * DH + d];
  }
  __syncthreads();
  float eh[2];
  eh[0] = EH[(size_t)node * DH + tid];
  eh[1] = EH[(size_t)node * DH + tid + 256];
  float ka[KNB] = {0, 0, 0, 0, 0, 0};
#pragma unroll
  for (int t = 0; t < 2; ++t) {
    const int d = tid + t * 256;
    const float e_ = eh[t];
#pragma unroll
    for (int k = 0; k < KNB; ++k) {
      float Nb = sNb[k][d];
      float ehr = pk[k] * Nb + (1.f - pk[k]) * e_;
      float g = tanhf(e_ + ehr);
      ka[k] = fmaf(Nb, g, ka[k]);
    }
  }
#pragma unroll
  for (int k = 0; k < KNB; ++k) {
    float v = ka[k];
#pragma unroll
    for (int off = 32; off > 0; off >>= 1) v += __shfl_down(v, off, 64);
    if ((tid & 63) == 0) sred[tid >> 6][k] = v;
  }
  __syncthreads();
  if (tid < KNB) ska[tid] = sred[0][tid] + sred[1][tid] + sred[2][tid] + sred[3][tid];
  __syncthreads();
  float kav[KNB];
#pragma unroll
  for (int k = 0; k < KNB; ++k) kav[k] = ska[k];
  float kmx = kav[0];
#pragma unroll
  for (int k = 1; k < KNB; ++k) kmx = fmaxf(kmx, kav[k]);
  float kp[KNB];
  float ks = 0.f;
#pragma unroll
  for (int k = 0; k < KNB; ++k) { kp[k] = expf(kav[k] - kmx); ks += kp[k]; }
  const float inv_ks = 1.f / ks;
#pragma unroll
  for (int k = 0; k < KNB; ++k) kp[k] *= inv_ks;
#pragma unroll
  for (int t = 0; t < 2; ++t) {
    const int d = tid + t * 256;
    float eNh = 0.f;
#pragma unroll
    for (int k = 0; k < KNB; ++k) eNh = fmaf(kp[k], sNb[k][d], eNh);
    const float e_ = eh[t];
    U[(size_t)node * DH + d] = e_ + eNh;
    V[(size_t)node * DH + d] = e_ * eNh;
  }
}

// a[n] = dot(hid[n], att2_w) + att2_b ; one wave per node
__global__ __launch_bounds__(256) void att_dot(const float* __restrict__ HID,
                                               const float* __restrict__ w2,
                                               const float* __restrict__ b2,
                                               float* __restrict__ a) {
  const int wid = threadIdx.x >> 6, lane = threadIdx.x & 63;
  const int node = blockIdx.x * 4 + wid;
  const float4 h4 = *reinterpret_cast<const float4*>(HID + (size_t)node * 256 + lane * 4);
  const float4 w4 = *reinterpret_cast<const float4*>(w2 + lane * 4);
  float s = h4.x * w4.x + h4.y * w4.y + h4.z * w4.z + h4.w * w4.w;
#pragma unroll
  for (int off = 32; off > 0; off >>= 1) s += __shfl_down(s, off, 64);
  if (lane == 0) a[node] = s + b2[0];
}

// global softmax stats over a[8192]
__global__ __launch_bounds__(1024) void softmax_stats(const float* __restrict__ a,
                                                      float* __restrict__ st) {
  __shared__ float red[16];
  __shared__ float bc;
  const int tid = threadIdx.x;
  float mx = -3.4e38f;
  for (int i = tid; i < N_NODES; i += 1024) mx = fmaxf(mx, a[i]);
#pragma unroll
  for (int off = 32; off > 0; off >>= 1) mx = fmaxf(mx, __shfl_xor(mx, off, 64));
  if ((tid & 63) == 0) red[tid >> 6] = mx;
  __syncthreads();
  if (tid == 0) {
    float m = red[0];
    for (int i = 1; i < 16; ++i) m = fmaxf(m, red[i]);
    bc = m;
  }
  __syncthreads();
  const float gm = bc;
  float se = 0.f;
  for (int i = tid; i < N_NODES; i += 1024) se += expf(a[i] - gm);
#pragma unroll
  for (int off = 32; off > 0; off >>= 1) se += __shfl_xor(se, off, 64);
  if ((tid & 63) == 0) red[tid >> 6] = se;
  __syncthreads();
  if (tid == 0) {
    float s = 0.f;
    for (int i = 0; i < 16; ++i) s += red[i];
    st[0] = gm;
    st[1] = s;
  }
}

// h[c] = sum_n softmax(a)_n * emb[n][c]   (atomicAdd partials)
__global__ __launch_bounds__(256) void readout(const float* __restrict__ EMB,
                                               const float* __restrict__ a,
                                               const float* __restrict__ st,
                                               float* __restrict__ h) {
  __shared__ float sacc[4][64];
  const int tid = threadIdx.x;
  const int c = (blockIdx.x << 6) + (tid & 63);
  const int rsub = tid >> 6;
  const float mx = st[0], inv_se = 1.f / st[1];
  const int r0 = blockIdx.y << 8;
  float acc = 0.f;
  for (int i = 0; i < 64; ++i) {
    const int r = r0 + (i << 2) + rsub;
    const float g = expf(a[r] - mx);
    acc = fmaf(g, EMB[(size_t)r * DH + c], acc);
  }
  sacc[rsub][tid & 63] = acc * inv_se;
  __syncthreads();
  if (rsub == 0) {
    float t = sacc[0][tid] + sacc[1][tid] + sacc[2][tid] + sacc[3][tid];
    atomicAdd(&h[c], t);
  }
}

// layernorm + final fc -> 2 logits
__global__ __launch_bounds__(512) void finalize(const float* __restrict__ h,
                                                const float* __restrict__ ln_g,
                                                const float* __restrict__ ln_b,
                                                const float* __restrict__ fc_w,
                                                const float* __restrict__ fc_b,
                                                float* __restrict__ out) {
  __shared__ float red0[8];
  __shared__ float red1[8];
  __shared__ float bc[2];
  const int tid = threadIdx.x;
  const int wid = tid >> 6, lane = tid & 63;
  const float v = h[tid];
  float s = v;
#pragma unroll
  for (int off = 32; off > 0; off >>= 1) s += __shfl_xor(s, off, 64);
  if (lane == 0) red0[wid] = s;
  __syncthreads();
  if (tid == 0) {
    float t = 0.f;
    for (int i = 0; i < 8; ++i) t += red0[i];
    bc[0] = t * (1.f / 512.f);
  }
  __syncthreads();
  const float mu = bc[0];
  const float dv = v - mu;
  s = dv * dv;
#pragma unroll
  for (int off = 32; off > 0; off >>= 1) s += __shfl_xor(s, off, 64);
  if (lane == 0) red0[wid] = s;
  __syncthreads();
  if (tid == 0) {
    float t = 0.f;
    for (int i = 0; i < 8; ++i) t += red0[i];
    bc[1] = t * (1.f / 512.f);
  }
  __syncthreads();
  const float var = bc[1];
  const float hn = dv / sqrtf(var + 1e-5f) * ln_g[tid] + ln_b[tid];
  float l0 = hn * fc_w[tid * 2 + 0];
  float l1 = hn * fc_w[tid * 2 + 1];
#pragma unroll
  for (int off = 32; off > 0; off >>= 1) {
    l0 += __shfl_xor(l0, off, 64);
    l1 += __shfl_xor(l1, off, 64);
  }
  if (lane == 0) { red0[wid] = l0; red1[wid] = l1; }
  __syncthreads();
  if (tid == 0) {
    float t0 = 0.f, t1 = 0.f;
    for (int i = 0; i < 8; ++i) { t0 += red0[i]; t1 += red1[i]; }
    out[0] = t0 + fc_b[0];
    out[1] = t1 + fc_b[1];
  }
}

// ---------------------------------------------------------------------------
extern "C" void kernel_launch(void* const* d_in, const int* in_sizes, int n_in,
                              void* d_out, int out_size, void* d_ws, size_t ws_size,
                              hipStream_t stream) {
  const float* x_s    = (const float*)d_in[0];
  const float* fc1_w  = (const float*)d_in[1];
  const float* fc1_b  = (const float*)d_in[2];
  const float* wh_w   = (const float*)d_in[3];
  const float* wh_b   = (const float*)d_in[4];
  const float* wt_w   = (const float*)d_in[5];
  const float* wt_b   = (const float*)d_in[6];
  const float* l1_w   = (const float*)d_in[7];
  const float* l1_b   = (const float*)d_in[8];
  const float* l2_w   = (const float*)d_in[9];
  const float* l2_b   = (const float*)d_in[10];
  const float* att1_w = (const float*)d_in[11];
  const float* att1_b = (const float*)d_in[12];
  const float* att2_w = (const float*)d_in[13];
  const float* att2_b = (const float*)d_in[14];
  const float* ln_g   = (const float*)d_in[15];
  const float* ln_b   = (const float*)d_in[16];
  const float* fc_w   = (const float*)d_in[17];
  const float* fc_b   = (const float*)d_in[18];

  float* ws = (float*)d_ws;
  const size_t BIG = (size_t)N_NODES * DH;  // 4,194,304
  float* B0 = ws;                // x, then u
  float* B1 = ws + BIG;          // e_h, then emb
  float* B2 = ws + 2 * BIG;      // e_t, then hid
  float* B3 = ws + 3 * BIG;      // v
  float* tkv    = ws + 4 * BIG;               // 2*8192*6
  int*   tki    = (int*)(tkv + 2 * N_NODES * 6);
  float* fwv    = (float*)(tki + 2 * N_NODES * 6);
  int*   fiv    = (int*)(fwv + N_NODES * 6);
  float* colsum = (float*)(fiv + N_NODES * 6);
  float* av     = colsum + DH;
  float* stats  = av + N_NODES;
  float* hbuf   = stats + 16;

  // 1. x = lrelu(x_s @ fc1_w + b)
  gemm64<1, 0><<<dim3(8, 128), 256, 0, stream>>>(x_s, fc1_w, fc1_b, B0, N_NODES, DIN, DH);
  // 2. mean-mix
  hipMemsetAsync(colsum, 0, DH * sizeof(float), stream);
  colsum_kernel<<<64, 256, 0, stream>>>(B0, colsum);
  mix_kernel<<<4096, 256, 0, stream>>>(B0, colsum);
  // 3. e_h, e_t
  gemm64<0, 0><<<dim3(8, 128), 256, 0, stream>>>(B0, wh_w, wh_b, B1, N_NODES, DH, DH);
  gemm64<0, 0><<<dim3(8, 128), 256, 0, stream>>>(B0, wt_w, wt_b, B2, N_NODES, DH, DH);
  // 4. scoring + streaming top-6
  score_topk<<<dim3(2, 128), 256, 0, stream>>>(B1, B2, tkv, tki);
  merge_topk<<<32, 256, 0, stream>>>(tkv, tki, fwv, fiv);
  // 5. neighbor aggregation -> U (in B0), V (in B3)
  agg_kernel<<<N_NODES, 256, 0, stream>>>(B1, B2, fwv, fiv, B0, B3);
  // 6. emb = lrelu(U@l1+b1) + lrelu(V@l2+b2)  -> B1
  gemm64<1, 0><<<dim3(8, 128), 256, 0, stream>>>(B0, l1_w, l1_b, B1, N_NODES, DH, DH);
  gemm64<1, 1><<<dim3(8, 128), 256, 0, stream>>>(B3, l2_w, l2_b, B1, N_NODES, DH, DH);
  // 7. attention readout
  gemm64<1, 0><<<dim3(4, 128), 256, 0, stream>>>(B1, att1_w, att1_b, B2, N_NODES, DH, 256);
  att_dot<<<2048, 256, 0, stream>>>(B2, att2_w, att2_b, av);
  softmax_stats<<<1, 1024, 0, stream>>>(av, stats);
  hipMemsetAsync(hbuf, 0, DH * sizeof(float), stream);
  readout<<<dim3(8, 32), 256, 0, stream>>>(B1, av, stats, hbuf);
  // 8. layernorm + logits
  finalize<<<1, 512, 0, stream>>>(hbuf, ln_g, ln_b, fc_w, fc_b, (float*)d_out);
}

// Round 3
// 772.755 us; speedup vs baseline: 2.8200x; 2.8200x over previous
//
#include <hip/hip_runtime.h>
#include <hip/hip_bf16.h>
#include <math.h>

#define N_NODES 8192
#define DIN 384
#define DH 512
#define KNB 6
#define NEG_SLOPE 0.01f

typedef __attribute__((ext_vector_type(8))) short bf16x8;
typedef __attribute__((ext_vector_type(4))) float f32x4;

__device__ __forceinline__ unsigned short f2bf(float x) {
  unsigned int u = __float_as_uint(x);
  unsigned int r = (u + 0x7fffu + ((u >> 16) & 1u)) >> 16;  // RNE
  return (unsigned short)r;
}

// ---------------------------------------------------------------------------
// Generic 64x64-tile fp32 GEMM: C = act(A[MxK] @ W[KxN] + bias) (+C if ACC)
// ---------------------------------------------------------------------------
template <int ACT, int ACC>
__global__ __launch_bounds__(256) void gemm64(const float* __restrict__ A,
                                              const float* __restrict__ W,
                                              const float* __restrict__ bias,
                                              float* __restrict__ C,
                                              int M, int K, int N) {
  __shared__ float sA[32][68];  // [k][row]
  __shared__ float sB[32][68];  // [k][col]
  const int tid = threadIdx.x;
  const int ty = tid >> 4, tx = tid & 15;
  const int row0 = blockIdx.y << 6;
  const int col0 = blockIdx.x << 6;
  float acc[4][4] = {};
  for (int kk = 0; kk < K; kk += 32) {
#pragma unroll
    for (int L = 0; L < 2; ++L) {
      int e = (tid + (L << 8)) << 2;  // 0..2044, step 4
      int r = e >> 5, c = e & 31;
      const float4 a4 = *reinterpret_cast<const float4*>(A + (size_t)(row0 + r) * K + kk + c);
      sA[c + 0][r] = a4.x; sA[c + 1][r] = a4.y; sA[c + 2][r] = a4.z; sA[c + 3][r] = a4.w;
      int kr = e >> 6, cc = e & 63;
      *reinterpret_cast<float4*>(&sB[kr][cc]) =
          *reinterpret_cast<const float4*>(W + (size_t)(kk + kr) * N + col0 + cc);
    }
    __syncthreads();
#pragma unroll
    for (int k = 0; k < 32; ++k) {
      float4 av = *reinterpret_cast<float4*>(&sA[k][ty << 2]);
      float4 bv = *reinterpret_cast<float4*>(&sB[k][tx << 2]);
      float aa[4] = {av.x, av.y, av.z, av.w};
      float bb[4] = {bv.x, bv.y, bv.z, bv.w};
#pragma unroll
      for (int i = 0; i < 4; ++i)
#pragma unroll
        for (int j = 0; j < 4; ++j) acc[i][j] = fmaf(aa[i], bb[j], acc[i][j]);
    }
    __syncthreads();
  }
#pragma unroll
  for (int i = 0; i < 4; ++i) {
    int r = row0 + (ty << 2) + i;
    int c = col0 + (tx << 2);
    float4 o;
    float vals[4];
#pragma unroll
    for (int j = 0; j < 4; ++j) {
      float v = acc[i][j] + bias[c + j];
      if (ACT == 1) v = v > 0.f ? v : NEG_SLOPE * v;
      vals[j] = v;
    }
    o.x = vals[0]; o.y = vals[1]; o.z = vals[2]; o.w = vals[3];
    float4* dst = reinterpret_cast<float4*>(C + (size_t)r * N + c);
    if (ACC) {
      float4 old = *dst;
      o.x += old.x; o.y += old.y; o.z += old.z; o.w += old.w;
    }
    *dst = o;
  }
}

// ---------------------------------------------------------------------------
// Column sums of X[8192 x 512]
// ---------------------------------------------------------------------------
__global__ __launch_bounds__(256) void colsum_kernel(const float* __restrict__ X,
                                                     float* __restrict__ cs) {
  const int tid = threadIdx.x;
  float s0 = 0.f, s1 = 0.f;
  const int r0 = blockIdx.x * 128;
  for (int r = r0; r < r0 + 128; ++r) {
    s0 += X[(size_t)r * DH + tid];
    s1 += X[(size_t)r * DH + tid + 256];
  }
  atomicAdd(&cs[tid], s0);
  atomicAdd(&cs[tid + 256], s1);
}

// x = (x + colmean) * 0.5
__global__ __launch_bounds__(256) void mix_kernel(float* __restrict__ X,
                                                  const float* __restrict__ cs) {
  const int gid = blockIdx.x * 256 + threadIdx.x;
  const int c4 = (gid & 127) << 2;
  float4 x = *reinterpret_cast<float4*>(X + (size_t)gid * 4);
  const float inv = 1.f / 8192.f;
  x.x = (x.x + cs[c4 + 0] * inv) * 0.5f;
  x.y = (x.y + cs[c4 + 1] * inv) * 0.5f;
  x.z = (x.z + cs[c4 + 2] * inv) * 0.5f;
  x.w = (x.w + cs[c4 + 3] * inv) * 0.5f;
  *reinterpret_cast<float4*>(X + (size_t)gid * 4) = x;
}

// eh (scaled by 512^-0.5) and et -> bf16 copies
__global__ __launch_bounds__(256) void convert_bf16(const float* __restrict__ eh,
                                                    const float* __restrict__ et,
                                                    unsigned short* __restrict__ ehb,
                                                    unsigned short* __restrict__ etb) {
  const float scale = 0.044194173824159216f;
  const size_t i = ((size_t)blockIdx.x * 256 + threadIdx.x) * 4;
  const float4 a = *reinterpret_cast<const float4*>(eh + i);
  const float4 b = *reinterpret_cast<const float4*>(et + i);
  ushort4 oa, ob;
  oa.x = f2bf(a.x * scale); oa.y = f2bf(a.y * scale);
  oa.z = f2bf(a.z * scale); oa.w = f2bf(a.w * scale);
  ob.x = f2bf(b.x); ob.y = f2bf(b.y); ob.z = f2bf(b.z); ob.w = f2bf(b.w);
  *reinterpret_cast<ushort4*>(ehb + i) = oa;
  *reinterpret_cast<ushort4*>(etb + i) = ob;
}

// ---------------------------------------------------------------------------
// MFMA scoring + streaming top-6.
// grid (2 j-splits, 256 row-blocks), block 256 (4 waves).
// Block = 32 rows; A frags (32 x 512) held in VGPRs (2x16 frags).
// Each wave owns a 64-col strip per 256-col j-iter; B frags loaded per-lane
// direct from global (L2-resident). Scores dumped per-wave to LDS [col][row]
// (stride 36, conflict-free scan), scanned wave-synchronously; per-lane
// top-6 over a fixed (row, col-half) partition; 8-way merge at end.
// ---------------------------------------------------------------------------
__global__ __launch_bounds__(256, 1) void score_topk_mfma(
    const unsigned short* __restrict__ EHb, const unsigned short* __restrict__ ETb,
    float* __restrict__ tkv, int* __restrict__ tki) {
  __shared__ float swbuf[4 * 64 * 36];  // 36.9 KB
  const int tid = threadIdx.x;
  const int wave = tid >> 6, lane = tid & 63;
  const int lo16 = lane & 15, hi = lane >> 4;
  const int grow0 = blockIdx.y << 5;   // 32 rows per block
  const int jbase = blockIdx.x << 12;  // j-split of 4096

  // A fragments: rows [grow0, grow0+32), full K in registers (128 VGPR)
  bf16x8 af[2][16];
#pragma unroll
  for (int rt = 0; rt < 2; ++rt)
#pragma unroll
    for (int kk = 0; kk < 16; ++kk)
      af[rt][kk] = *reinterpret_cast<const bf16x8*>(
          EHb + (size_t)(grow0 + rt * 16 + lo16) * DH + kk * 32 + hi * 8);

  float tv[6];
  int ti[6];
#pragma unroll
  for (int s = 0; s < 6; ++s) { tv[s] = -3.4e38f; ti[s] = 0; }

  float* sw = swbuf + wave * (64 * 36);
  const int scanr = lane & 31, scanh = lane >> 5;

  for (int jt = 0; jt < 16; ++jt) {
    const int wcol0 = jbase + jt * 256 + wave * 64;
    f32x4 acc[2][4];
#pragma unroll
    for (int rt = 0; rt < 2; ++rt)
#pragma unroll
      for (int ct = 0; ct < 4; ++ct) {
        acc[rt][ct].x = 0.f; acc[rt][ct].y = 0.f;
        acc[rt][ct].z = 0.f; acc[rt][ct].w = 0.f;
      }
#pragma unroll
    for (int kk = 0; kk < 16; ++kk) {
      bf16x8 bfr[4];
#pragma unroll
      for (int ct = 0; ct < 4; ++ct)
        bfr[ct] = *reinterpret_cast<const bf16x8*>(
            ETb + (size_t)(wcol0 + ct * 16 + lo16) * DH + kk * 32 + hi * 8);
#pragma unroll
      for (int ct = 0; ct < 4; ++ct)
#pragma unroll
        for (int rt = 0; rt < 2; ++rt)
          acc[rt][ct] = __builtin_amdgcn_mfma_f32_16x16x32_bf16(
              af[rt][kk], bfr[ct], acc[rt][ct], 0, 0, 0);
    }
    // dump wave's 32x64 scores to LDS, [col][row] stride 36 (16B-aligned b128)
#pragma unroll
    for (int ct = 0; ct < 4; ++ct)
#pragma unroll
      for (int rt = 0; rt < 2; ++rt)
        *reinterpret_cast<f32x4*>(sw + (ct * 16 + lo16) * 36 + rt * 16 + hi * 4) =
            acc[rt][ct];
    asm volatile("s_waitcnt lgkmcnt(0)" ::: "memory");
    // scan: lane covers row (lane&31), col-half (lane>>5)*32 .. +32
#pragma unroll
    for (int cc = 0; cc < 32; ++cc) {
      const float v = sw[(scanh * 32 + cc) * 36 + scanr];
      const int col = wcol0 + scanh * 32 + cc;
      if (v > tv[5]) {
        tv[5] = v; ti[5] = col;
#pragma unroll
        for (int p = 5; p > 0; --p) {
          if (tv[p] > tv[p - 1]) {
            float tvt = tv[p]; tv[p] = tv[p - 1]; tv[p - 1] = tvt;
            int tit = ti[p]; ti[p] = ti[p - 1]; ti[p - 1] = tit;
          }
        }
      }
    }
    asm volatile("s_waitcnt lgkmcnt(0)" ::: "memory");
  }
  __syncthreads();
  // merge 8 partial lists (4 waves x 2 halves) per row
  float* mv = swbuf;                                   // [32][8][6]
  int* mi = reinterpret_cast<int*>(swbuf + 32 * 8 * 6);
  {
    const int li = wave * 2 + scanh;
#pragma unroll
    for (int s = 0; s < 6; ++s) {
      mv[(scanr * 8 + li) * 6 + s] = tv[s];
      mi[(scanr * 8 + li) * 6 + s] = ti[s];
    }
  }
  __syncthreads();
  if (tid < 32) {
    int pq[8] = {0, 0, 0, 0, 0, 0, 0, 0};
    const int base = (blockIdx.x * N_NODES + grow0 + tid) * 6;
    for (int s = 0; s < 6; ++s) {
      float best = -3.4e38f;
      int bi = 0x7fffffff, bq = -1;
#pragma unroll
      for (int q = 0; q < 8; ++q) {
        if (pq[q] < 6) {
          const float v = mv[(tid * 8 + q) * 6 + pq[q]];
          const int ix = mi[(tid * 8 + q) * 6 + pq[q]];
          if (v > best || (v == best && ix < bi)) { best = v; bi = ix; bq = q; }
        }
      }
      tkv[base + s] = best;
      tki[base + s] = bi;
#pragma unroll
      for (int q = 0; q < 8; ++q) pq[q] += (bq == q) ? 1 : 0;
    }
  }
}

// merge the two j-split top-6 lists into final top-6
__global__ __launch_bounds__(256) void merge_topk(const float* __restrict__ tkv,
                                                  const int* __restrict__ tki,
                                                  float* __restrict__ fw,
                                                  int* __restrict__ fi) {
  const int n = blockIdx.x * 256 + threadIdx.x;
  const float* v0 = tkv + (size_t)n * 6;
  const int* i0 = tki + (size_t)n * 6;
  const float* v1 = tkv + (size_t)(N_NODES + n) * 6;
  const int* i1 = tki + (size_t)(N_NODES + n) * 6;
  int p0 = 0, p1 = 0;
  for (int s = 0; s < 6; ++s) {
    float a = v0[p0], b = v1[p1];
    int ia = i0[p0], ib = i1[p1];
    bool takeA = (a > b) || (a == b && ia < ib);
    if (takeA) { fw[n * 6 + s] = a; fi[n * 6 + s] = ia; ++p0; }
    else       { fw[n * 6 + s] = b; fi[n * 6 + s] = ib; ++p1; }
  }
}

// ---------------------------------------------------------------------------
// Per-node neighbor aggregation (unchanged)
// ---------------------------------------------------------------------------
__global__ __launch_bounds__(256) void agg_kernel(const float* __restrict__ EH,
                                                  const float* __restrict__ ET,
                                                  const float* __restrict__ fw,
                                                  const int* __restrict__ fi,
                                                  float* __restrict__ U,
                                                  float* __restrict__ V) {
  __shared__ float sNb[KNB][DH];
  __shared__ float sred[4][8];
  __shared__ float ska[8];
  const int node = blockIdx.x;
  const int tid = threadIdx.x;
  float w[KNB];
  int idx[KNB];
#pragma unroll
  for (int k = 0; k < KNB; ++k) {
    w[k] = fw[node * KNB + k];
    idx[k] = fi[node * KNB + k];
  }
  float mx = w[0];
#pragma unroll
  for (int k = 1; k < KNB; ++k) mx = fmaxf(mx, w[k]);
  float pk[KNB];
  float se = 0.f;
#pragma unroll
  for (int k = 0; k < KNB; ++k) { pk[k] = expf(w[k] - mx); se += pk[k]; }
  const float inv_se = 1.f / se;
#pragma unroll
  for (int k = 0; k < KNB; ++k) pk[k] *= inv_se;
  for (int e = tid; e < KNB * DH; e += 256) {
    int k = e >> 9, d = e & 511;
    sNb[k][d] = ET[(size_t)idx[k] * DH + d];
  }
  __syncthreads();
  float eh[2];
  eh[0] = EH[(size_t)node * DH + tid];
  eh[1] = EH[(size_t)node * DH + tid + 256];
  float ka[KNB] = {0, 0, 0, 0, 0, 0};
#pragma unroll
  for (int t = 0; t < 2; ++t) {
    const int d = tid + t * 256;
    const float e_ = eh[t];
#pragma unroll
    for (int k = 0; k < KNB; ++k) {
      float Nb = sNb[k][d];
      float ehr = pk[k] * Nb + (1.f - pk[k]) * e_;
      float g = tanhf(e_ + ehr);
      ka[k] = fmaf(Nb, g, ka[k]);
    }
  }
#pragma unroll
  for (int k = 0; k < KNB; ++k) {
    float v = ka[k];
#pragma unroll
    for (int off = 32; off > 0; off >>= 1) v += __shfl_down(v, off, 64);
    if ((tid & 63) == 0) sred[tid >> 6][k] = v;
  }
  __syncthreads();
  if (tid < KNB) ska[tid] = sred[0][tid] + sred[1][tid] + sred[2][tid] + sred[3][tid];
  __syncthreads();
  float kav[KNB];
#pragma unroll
  for (int k = 0; k < KNB; ++k) kav[k] = ska[k];
  float kmx = kav[0];
#pragma unroll
  for (int k = 1; k < KNB; ++k) kmx = fmaxf(kmx, kav[k]);
  float kp[KNB];
  float ks = 0.f;
#pragma unroll
  for (int k = 0; k < KNB; ++k) { kp[k] = expf(kav[k] - kmx); ks += kp[k]; }
  const float inv_ks = 1.f / ks;
#pragma unroll
  for (int k = 0; k < KNB; ++k) kp[k] *= inv_ks;
#pragma unroll
  for (int t = 0; t < 2; ++t) {
    const int d = tid + t * 256;
    float eNh = 0.f;
#pragma unroll
    for (int k = 0; k < KNB; ++k) eNh = fmaf(kp[k], sNb[k][d], eNh);
    const float e_ = eh[t];
    U[(size_t)node * DH + d] = e_ + eNh;
    V[(size_t)node * DH + d] = e_ * eNh;
  }
}

// a[n] = dot(hid[n], att2_w) + att2_b ; one wave per node
__global__ __launch_bounds__(256) void att_dot(const float* __restrict__ HID,
                                               const float* __restrict__ w2,
                                               const float* __restrict__ b2,
                                               float* __restrict__ a) {
  const int wid = threadIdx.x >> 6, lane = threadIdx.x & 63;
  const int node = blockIdx.x * 4 + wid;
  const float4 h4 = *reinterpret_cast<const float4*>(HID + (size_t)node * 256 + lane * 4);
  const float4 w4 = *reinterpret_cast<const float4*>(w2 + lane * 4);
  float s = h4.x * w4.x + h4.y * w4.y + h4.z * w4.z + h4.w * w4.w;
#pragma unroll
  for (int off = 32; off > 0; off >>= 1) s += __shfl_down(s, off, 64);
  if (lane == 0) a[node] = s + b2[0];
}

// global softmax stats over a[8192]
__global__ __launch_bounds__(1024) void softmax_stats(const float* __restrict__ a,
                                                      float* __restrict__ st) {
  __shared__ float red[16];
  __shared__ float bc;
  const int tid = threadIdx.x;
  float mx = -3.4e38f;
  for (int i = tid; i < N_NODES; i += 1024) mx = fmaxf(mx, a[i]);
#pragma unroll
  for (int off = 32; off > 0; off >>= 1) mx = fmaxf(mx, __shfl_xor(mx, off, 64));
  if ((tid & 63) == 0) red[tid >> 6] = mx;
  __syncthreads();
  if (tid == 0) {
    float m = red[0];
    for (int i = 1; i < 16; ++i) m = fmaxf(m, red[i]);
    bc = m;
  }
  __syncthreads();
  const float gm = bc;
  float se = 0.f;
  for (int i = tid; i < N_NODES; i += 1024) se += expf(a[i] - gm);
#pragma unroll
  for (int off = 32; off > 0; off >>= 1) se += __shfl_xor(se, off, 64);
  if ((tid & 63) == 0) red[tid >> 6] = se;
  __syncthreads();
  if (tid == 0) {
    float s = 0.f;
    for (int i = 0; i < 16; ++i) s += red[i];
    st[0] = gm;
    st[1] = s;
  }
}

// h[c] = sum_n softmax(a)_n * emb[n][c]
__global__ __launch_bounds__(256) void readout(const float* __restrict__ EMB,
                                               const float* __restrict__ a,
                                               const float* __restrict__ st,
                                               float* __restrict__ h) {
  __shared__ float sacc[4][64];
  const int tid = threadIdx.x;
  const int c = (blockIdx.x << 6) + (tid & 63);
  const int rsub = tid >> 6;
  const float mx = st[0], inv_se = 1.f / st[1];
  const int r0 = blockIdx.y << 8;
  float acc = 0.f;
  for (int i = 0; i < 64; ++i) {
    const int r = r0 + (i << 2) + rsub;
    const float g = expf(a[r] - mx);
    acc = fmaf(g, EMB[(size_t)r * DH + c], acc);
  }
  sacc[rsub][tid & 63] = acc * inv_se;
  __syncthreads();
  if (rsub == 0) {
    float t = sacc[0][tid] + sacc[1][tid] + sacc[2][tid] + sacc[3][tid];
    atomicAdd(&h[c], t);
  }
}

// layernorm + final fc -> 2 logits
__global__ __launch_bounds__(512) void finalize(const float* __restrict__ h,
                                                const float* __restrict__ ln_g,
                                                const float* __restrict__ ln_b,
                                                const float* __restrict__ fc_w,
                                                const float* __restrict__ fc_b,
                                                float* __restrict__ out) {
  __shared__ float red0[8];
  __shared__ float red1[8];
  __shared__ float bc[2];
  const int tid = threadIdx.x;
  const int wid = tid >> 6, lane = tid & 63;
  const float v = h[tid];
  float s = v;
#pragma unroll
  for (int off = 32; off > 0; off >>= 1) s += __shfl_xor(s, off, 64);
  if (lane == 0) red0[wid] = s;
  __syncthreads();
  if (tid == 0) {
    float t = 0.f;
    for (int i = 0; i < 8; ++i) t += red0[i];
    bc[0] = t * (1.f / 512.f);
  }
  __syncthreads();
  const float mu = bc[0];
  const float dv = v - mu;
  s = dv * dv;
#pragma unroll
  for (int off = 32; off > 0; off >>= 1) s += __shfl_xor(s, off, 64);
  if (lane == 0) red0[wid] = s;
  __syncthreads();
  if (tid == 0) {
    float t = 0.f;
    for (int i = 0; i < 8; ++i) t += red0[i];
    bc[1] = t * (1.f / 512.f);
  }
  __syncthreads();
  const float var = bc[1];
  const float hn = dv / sqrtf(var + 1e-5f) * ln_g[tid] + ln_b[tid];
  float l0 = hn * fc_w[tid * 2 + 0];
  float l1 = hn * fc_w[tid * 2 + 1];
#pragma unroll
  for (int off = 32; off > 0; off >>= 1) {
    l0 += __shfl_xor(l0, off, 64);
    l1 += __shfl_xor(l1, off, 64);
  }
  if (lane == 0) { red0[wid] = l0; red1[wid] = l1; }
  __syncthreads();
  if (tid == 0) {
    float t0 = 0.f, t1 = 0.f;
    for (int i = 0; i < 8; ++i) { t0 += red0[i]; t1 += red1[i]; }
    out[0] = t0 + fc_b[0];
    out[1] = t1 + fc_b[1];
  }
}

// ---------------------------------------------------------------------------
extern "C" void kernel_launch(void* const* d_in, const int* in_sizes, int n_in,
                              void* d_out, int out_size, void* d_ws, size_t ws_size,
                              hipStream_t stream) {
  const float* x_s    = (const float*)d_in[0];
  const float* fc1_w  = (const float*)d_in[1];
  const float* fc1_b  = (const float*)d_in[2];
  const float* wh_w   = (const float*)d_in[3];
  const float* wh_b   = (const float*)d_in[4];
  const float* wt_w   = (const float*)d_in[5];
  const float* wt_b   = (const float*)d_in[6];
  const float* l1_w   = (const float*)d_in[7];
  const float* l1_b   = (const float*)d_in[8];
  const float* l2_w   = (const float*)d_in[9];
  const float* l2_b   = (const float*)d_in[10];
  const float* att1_w = (const float*)d_in[11];
  const float* att1_b = (const float*)d_in[12];
  const float* att2_w = (const float*)d_in[13];
  const float* att2_b = (const float*)d_in[14];
  const float* ln_g   = (const float*)d_in[15];
  const float* ln_b   = (const float*)d_in[16];
  const float* fc_w   = (const float*)d_in[17];
  const float* fc_b   = (const float*)d_in[18];

  float* ws = (float*)d_ws;
  const size_t BIG = (size_t)N_NODES * DH;  // 4,194,304 floats
  float* B0 = ws;                // x; then bf16 EHb/ETb; then u
  float* B1 = ws + BIG;          // e_h, then emb
  float* B2 = ws + 2 * BIG;      // e_t, then hid
  float* B3 = ws + 3 * BIG;      // v
  float* tkv    = ws + 4 * BIG;               // 2*8192*6
  int*   tki    = (int*)(tkv + 2 * N_NODES * 6);
  float* fwv    = (float*)(tki + 2 * N_NODES * 6);
  int*   fiv    = (int*)(fwv + N_NODES * 6);
  float* colsum = (float*)(fiv + N_NODES * 6);
  float* av     = colsum + DH;
  float* stats  = av + N_NODES;
  float* hbuf   = stats + 16;

  unsigned short* EHb = (unsigned short*)B0;          // 8 MB
  unsigned short* ETb = EHb + (size_t)N_NODES * DH;   // 8 MB (B0 is 16 MB)

  // 1. x = lrelu(x_s @ fc1_w + b)
  gemm64<1, 0><<<dim3(8, 128), 256, 0, stream>>>(x_s, fc1_w, fc1_b, B0, N_NODES, DIN, DH);
  // 2. mean-mix
  hipMemsetAsync(colsum, 0, DH * sizeof(float), stream);
  colsum_kernel<<<64, 256, 0, stream>>>(B0, colsum);
  mix_kernel<<<4096, 256, 0, stream>>>(B0, colsum);
  // 3. e_h, e_t
  gemm64<0, 0><<<dim3(8, 128), 256, 0, stream>>>(B0, wh_w, wh_b, B1, N_NODES, DH, DH);
  gemm64<0, 0><<<dim3(8, 128), 256, 0, stream>>>(B0, wt_w, wt_b, B2, N_NODES, DH, DH);
  // 4. bf16 copies (x dead now; reuse B0 region), then MFMA scoring + top-6
  convert_bf16<<<4096, 256, 0, stream>>>(B1, B2, EHb, ETb);
  score_topk_mfma<<<dim3(2, 256), 256, 0, stream>>>(EHb, ETb, tkv, tki);
  merge_topk<<<32, 256, 0, stream>>>(tkv, tki, fwv, fiv);
  // 5. neighbor aggregation -> U (in B0, clobbers bf16 copies), V (in B3)
  agg_kernel<<<N_NODES, 256, 0, stream>>>(B1, B2, fwv, fiv, B0, B3);
  // 6. emb = lrelu(U@l1+b1) + lrelu(V@l2+b2)  -> B1
  gemm64<1, 0><<<dim3(8, 128), 256, 0, stream>>>(B0, l1_w, l1_b, B1, N_NODES, DH, DH);
  gemm64<1, 1><<<dim3(8, 128), 256, 0, stream>>>(B3, l2_w, l2_b, B1, N_NODES, DH, DH);
  // 7. attention readout
  gemm64<1, 0><<<dim3(4, 128), 256, 0, stream>>>(B1, att1_w, att1_b, B2, N_NODES, DH, 256);
  att_dot<<<2048, 256, 0, stream>>>(B2, att2_w, att2_b, av);
  softmax_stats<<<1, 1024, 0, stream>>>(av, stats);
  hipMemsetAsync(hbuf, 0, DH * sizeof(float), stream);
  readout<<<dim3(8, 32), 256, 0, stream>>>(B1, av, stats, hbuf);
  // 8. layernorm + logits
  finalize<<<1, 512, 0, stream>>>(hbuf, ln_g, ln_b, fc_w, fc_b, (float*)d_out);
}

// Round 4
// 587.812 us; speedup vs baseline: 3.7073x; 1.3146x over previous
//
#include <hip/hip_runtime.h>
#include <hip/hip_bf16.h>
#include <math.h>

#define N_NODES 8192
#define DIN 384
#define DH 512
#define KNB 6
#define NEG_SLOPE 0.01f
#define NSPLIT 4

typedef __attribute__((ext_vector_type(8))) short bf16x8;
typedef __attribute__((ext_vector_type(4))) float f32x4;

__device__ __forceinline__ unsigned short f2bf(float x) {
  unsigned int u = __float_as_uint(x);
  unsigned int r = (u + 0x7fffu + ((u >> 16) & 1u)) >> 16;  // RNE
  return (unsigned short)r;
}
__device__ __forceinline__ float bf2f(unsigned short u) {
  return __uint_as_float(((unsigned int)u) << 16);
}

// ---------------------------------------------------------------------------
// Weight prep: W[K][N] fp32 -> Wt[N][K] bf16, all 6 weights into one pool.
// Writes coalesced u16; strided reads absorbed by L2 (weights ~5.5 MB).
// ---------------------------------------------------------------------------
__global__ __launch_bounds__(256) void prep_weights(
    const float* __restrict__ w0, const float* __restrict__ w1,
    const float* __restrict__ w2, const float* __restrict__ w3,
    const float* __restrict__ w4, const float* __restrict__ w5,
    unsigned short* __restrict__ pool) {
  const int f = blockIdx.x * 256 + threadIdx.x;
  const int E0 = 196608, E1 = 458752, E2 = 720896, E3 = 983040, E4 = 1245184, E5 = 1376256;
  if (f >= E5) return;
  const float* src; int off, Kw, Nw;
  if (f < E0)      { src = w0; off = 0;  Kw = 384; Nw = 512; }
  else if (f < E1) { src = w1; off = E0; Kw = 512; Nw = 512; }
  else if (f < E2) { src = w2; off = E1; Kw = 512; Nw = 512; }
  else if (f < E3) { src = w3; off = E2; Kw = 512; Nw = 512; }
  else if (f < E4) { src = w4; off = E3; Kw = 512; Nw = 512; }
  else             { src = w5; off = E4; Kw = 512; Nw = 256; }
  const int local = f - off;
  const int n = local / Kw, k = local - n * Kw;
  pool[f] = f2bf(src[(size_t)k * Nw + n]);
}

// x_s fp32 -> bf16
__global__ __launch_bounds__(256) void convert_xs(const float* __restrict__ xs,
                                                  unsigned short* __restrict__ out) {
  const size_t i = ((size_t)blockIdx.x * 256 + threadIdx.x) * 4;
  const float4 v = *reinterpret_cast<const float4*>(xs + i);
  ushort4 o;
  o.x = f2bf(v.x); o.y = f2bf(v.y); o.z = f2bf(v.z); o.w = f2bf(v.w);
  *reinterpret_cast<ushort4*>(out + i) = o;
}

// ---------------------------------------------------------------------------
// bf16 MFMA GEMM: C[M,N] = act(A[M,K]bf16 @ Wt[N,K]bf16^T + bias) variants.
// 64x64 tile, 4 waves, K-step 64, XOR-swizzled LDS, 16x16x32 MFMA.
// ---------------------------------------------------------------------------
template <int ACT, int ACC, int WF32, int WBF16>
__global__ __launch_bounds__(256) void gemm_bf16(
    const unsigned short* __restrict__ A, const unsigned short* __restrict__ Wt,
    const float* __restrict__ bias, float* __restrict__ C,
    unsigned short* __restrict__ Cb, float bscale, int M, int K, int N) {
  __shared__ unsigned short sa[64 * 64];
  __shared__ unsigned short sb[64 * 64];
  const int tid = threadIdx.x;
  const int wave = tid >> 6, lane = tid & 63;
  const int lo16 = lane & 15, hi = lane >> 4;
  const int row0 = blockIdx.y << 6, col0 = blockIdx.x << 6;
  f32x4 acc[4];
#pragma unroll
  for (int rt = 0; rt < 4; ++rt) { acc[rt].x = 0.f; acc[rt].y = 0.f; acc[rt].z = 0.f; acc[rt].w = 0.f; }
  for (int k0 = 0; k0 < K; k0 += 64) {
    __syncthreads();
#pragma unroll
    for (int i = 0; i < 2; ++i) {
      const int c = i * 256 + tid;
      const int r = c >> 3, i8 = c & 7;
      const bf16x8 va = *reinterpret_cast<const bf16x8*>(A + (size_t)(row0 + r) * K + k0 + i8 * 8);
      const bf16x8 vb = *reinterpret_cast<const bf16x8*>(Wt + (size_t)(col0 + r) * K + k0 + i8 * 8);
      const int byte = r * 128 + ((i8 * 16) ^ ((r & 7) << 4));
      *reinterpret_cast<bf16x8*>(reinterpret_cast<char*>(sa) + byte) = va;
      *reinterpret_cast<bf16x8*>(reinterpret_cast<char*>(sb) + byte) = vb;
    }
    __syncthreads();
#pragma unroll
    for (int kk2 = 0; kk2 < 2; ++kk2) {
      const int col = wave * 16 + lo16;
      const int bbyte = col * 128 + (((kk2 << 6) + (hi << 4)) ^ ((col & 7) << 4));
      const bf16x8 bf = *reinterpret_cast<const bf16x8*>(reinterpret_cast<const char*>(sb) + bbyte);
#pragma unroll
      for (int rt = 0; rt < 4; ++rt) {
        const int row = rt * 16 + lo16;
        const int abyte = row * 128 + (((kk2 << 6) + (hi << 4)) ^ ((row & 7) << 4));
        const bf16x8 af = *reinterpret_cast<const bf16x8*>(reinterpret_cast<const char*>(sa) + abyte);
        acc[rt] = __builtin_amdgcn_mfma_f32_16x16x32_bf16(af, bf, acc[rt], 0, 0, 0);
      }
    }
  }
  const int col = col0 + wave * 16 + lo16;
  const float bv = bias[col];
#pragma unroll
  for (int rt = 0; rt < 4; ++rt) {
#pragma unroll
    for (int j = 0; j < 4; ++j) {
      const int r = row0 + rt * 16 + hi * 4 + j;
      float v = acc[rt][j] + bv;
      if (ACT) v = v > 0.f ? v : NEG_SLOPE * v;
      if (ACC) v += C[(size_t)r * N + col];
      if (WF32) C[(size_t)r * N + col] = v;
      if (WBF16) Cb[(size_t)r * N + col] = f2bf(v * bscale);
    }
  }
}

// ---------------------------------------------------------------------------
// Column sums of X[8192 x 512]
// ---------------------------------------------------------------------------
__global__ __launch_bounds__(256) void colsum_kernel(const float* __restrict__ X,
                                                     float* __restrict__ cs) {
  const int tid = threadIdx.x;
  float s0 = 0.f, s1 = 0.f;
  const int r0 = blockIdx.x * 128;
  for (int r = r0; r < r0 + 128; ++r) {
    s0 += X[(size_t)r * DH + tid];
    s1 += X[(size_t)r * DH + tid + 256];
  }
  atomicAdd(&cs[tid], s0);
  atomicAdd(&cs[tid + 256], s1);
}

// x = (x + colmean) * 0.5 ; also emit bf16 copy
__global__ __launch_bounds__(256) void mix_kernel(float* __restrict__ X,
                                                  const float* __restrict__ cs,
                                                  unsigned short* __restrict__ Xb) {
  const size_t gid = (size_t)blockIdx.x * 256 + threadIdx.x;
  const int c4 = ((int)gid & 127) << 2;
  float4 x = *reinterpret_cast<float4*>(X + gid * 4);
  const float inv = 1.f / 8192.f;
  x.x = (x.x + cs[c4 + 0] * inv) * 0.5f;
  x.y = (x.y + cs[c4 + 1] * inv) * 0.5f;
  x.z = (x.z + cs[c4 + 2] * inv) * 0.5f;
  x.w = (x.w + cs[c4 + 3] * inv) * 0.5f;
  *reinterpret_cast<float4*>(X + gid * 4) = x;
  ushort4 o;
  o.x = f2bf(x.x); o.y = f2bf(x.y); o.z = f2bf(x.z); o.w = f2bf(x.w);
  *reinterpret_cast<ushort4*>(Xb + gid * 4) = o;
}

// ---------------------------------------------------------------------------
// MFMA scoring + streaming top-6, v2.
// grid (4 j-splits, 256 row-blocks), block 256 (4 waves), 32 rows/block.
// A (32x512) staged once in XOR-swizzled LDS; B per-lane from global with
// explicit next-kk prefetch; scores dumped per-wave to LDS in two 32-col
// passes (18.4 KB) and scanned wave-synchronously. LDS 51 KB -> 3 blocks/CU.
// ---------------------------------------------------------------------------
__global__ __launch_bounds__(256, 3) void score_topk_mfma(
    const unsigned short* __restrict__ EHb, const unsigned short* __restrict__ ETb,
    float* __restrict__ tkv, int* __restrict__ tki) {
  __shared__ unsigned short sa[32 * 512];   // 32 KB swizzled A tile
  __shared__ float swb[4][32 * 36];         // 18.4 KB score buf
  const int tid = threadIdx.x;
  const int wave = tid >> 6, lane = tid & 63;
  const int lo16 = lane & 15, hi = lane >> 4;
  const int grow0 = blockIdx.y << 5;
  const int jbase = blockIdx.x << 11;  // 4 splits x 2048 cols

  // stage A rows [grow0, grow0+32) swizzled
#pragma unroll
  for (int i = 0; i < 8; ++i) {
    const int c = i * 256 + tid;
    const int row = c >> 6, i8 = c & 63;
    const bf16x8 v = *reinterpret_cast<const bf16x8*>(EHb + (size_t)(grow0 + row) * DH + i8 * 8);
    const int byte = row * 1024 + ((i8 * 16) ^ ((row & 7) << 4));
    *reinterpret_cast<bf16x8*>(reinterpret_cast<char*>(sa) + byte) = v;
  }
  __syncthreads();

  float tv[6];
  int ti[6];
#pragma unroll
  for (int s = 0; s < 6; ++s) { tv[s] = -3.4e38f; ti[s] = 0; }

  float* sw = swb[wave];
  const int scanr = lane & 31, scanh = lane >> 5;

  for (int jt = 0; jt < 8; ++jt) {
    const int wcol0 = jbase + jt * 256 + wave * 64;
    f32x4 acc[2][4];
#pragma unroll
    for (int rt = 0; rt < 2; ++rt)
#pragma unroll
      for (int ct = 0; ct < 4; ++ct) {
        acc[rt][ct].x = 0.f; acc[rt][ct].y = 0.f; acc[rt][ct].z = 0.f; acc[rt][ct].w = 0.f;
      }
    bf16x8 bcur[4];
#pragma unroll
    for (int ct = 0; ct < 4; ++ct)
      bcur[ct] = *reinterpret_cast<const bf16x8*>(
          ETb + (size_t)(wcol0 + ct * 16 + lo16) * DH + hi * 8);
#pragma unroll
    for (int kk = 0; kk < 16; ++kk) {
      const int kn = (kk + 1) & 15;  // kk=15 harmlessly reloads kk=0
      bf16x8 bnxt[4];
#pragma unroll
      for (int ct = 0; ct < 4; ++ct)
        bnxt[ct] = *reinterpret_cast<const bf16x8*>(
            ETb + (size_t)(wcol0 + ct * 16 + lo16) * DH + kn * 32 + hi * 8);
      const int inner = ((kk << 6) + (hi << 4));
      const int rowA0 = lo16;
      const int rowA1 = 16 + lo16;
      const bf16x8 a0 = *reinterpret_cast<const bf16x8*>(
          reinterpret_cast<const char*>(sa) + rowA0 * 1024 + (inner ^ ((rowA0 & 7) << 4)));
      const bf16x8 a1 = *reinterpret_cast<const bf16x8*>(
          reinterpret_cast<const char*>(sa) + rowA1 * 1024 + (inner ^ ((rowA1 & 7) << 4)));
#pragma unroll
      for (int ct = 0; ct < 4; ++ct) {
        acc[0][ct] = __builtin_amdgcn_mfma_f32_16x16x32_bf16(a0, bcur[ct], acc[0][ct], 0, 0, 0);
        acc[1][ct] = __builtin_amdgcn_mfma_f32_16x16x32_bf16(a1, bcur[ct], acc[1][ct], 0, 0, 0);
      }
#pragma unroll
      for (int ct = 0; ct < 4; ++ct) bcur[ct] = bnxt[ct];
    }
    // two 32-col dump+scan passes (wave-private region, wave-synchronous)
#pragma unroll
    for (int p = 0; p < 2; ++p) {
#pragma unroll
      for (int rt = 0; rt < 2; ++rt)
#pragma unroll
        for (int c2 = 0; c2 < 2; ++c2) {
          const int ct = p * 2 + c2;
          *reinterpret_cast<f32x4*>(sw + (c2 * 16 + lo16) * 36 + rt * 16 + hi * 4) = acc[rt][ct];
        }
      asm volatile("s_waitcnt lgkmcnt(0)" ::: "memory");
#pragma unroll
      for (int cc = 0; cc < 16; ++cc) {
        const float v = sw[(scanh * 16 + cc) * 36 + scanr];
        const int col = wcol0 + p * 32 + scanh * 16 + cc;
        if (v > tv[5]) {
          tv[5] = v; ti[5] = col;
#pragma unroll
          for (int q = 5; q > 0; --q) {
            if (tv[q] > tv[q - 1]) {
              float tvt = tv[q]; tv[q] = tv[q - 1]; tv[q - 1] = tvt;
              int tit = ti[q]; ti[q] = ti[q - 1]; ti[q - 1] = tit;
            }
          }
        }
      }
      asm volatile("s_waitcnt lgkmcnt(0)" ::: "memory");
    }
  }
  __syncthreads();
  // merge 8 partial lists (4 waves x 2 col-halves) per row
  float* mv = &swb[0][0];                          // [32][8][6]
  int* mi = reinterpret_cast<int*>(mv + 32 * 8 * 6);
  {
    const int li = wave * 2 + scanh;
#pragma unroll
    for (int s = 0; s < 6; ++s) {
      mv[(scanr * 8 + li) * 6 + s] = tv[s];
      mi[(scanr * 8 + li) * 6 + s] = ti[s];
    }
  }
  __syncthreads();
  if (tid < 32) {
    int pq[8] = {0, 0, 0, 0, 0, 0, 0, 0};
    const int base = (blockIdx.x * N_NODES + grow0 + tid) * 6;
    for (int s = 0; s < 6; ++s) {
      float best = -3.4e38f;
      int bi = 0x7fffffff, bq = 0;
#pragma unroll
      for (int q = 0; q < 8; ++q) {
        if (pq[q] < 6) {
          const float v = mv[(tid * 8 + q) * 6 + pq[q]];
          const int ix = mi[(tid * 8 + q) * 6 + pq[q]];
          if (v > best || (v == best && ix < bi)) { best = v; bi = ix; bq = q; }
        }
      }
      tkv[base + s] = best;
      tki[base + s] = bi;
#pragma unroll
      for (int q = 0; q < 8; ++q) pq[q] += (bq == q) ? 1 : 0;
    }
  }
}

// merge the 4 j-split top-6 lists into final top-6
__global__ __launch_bounds__(256) void merge_topk4(const float* __restrict__ tkv,
                                                   const int* __restrict__ tki,
                                                   float* __restrict__ fw,
                                                   int* __restrict__ fi) {
  const int n = blockIdx.x * 256 + threadIdx.x;
  int pq[NSPLIT] = {0, 0, 0, 0};
  for (int s = 0; s < 6; ++s) {
    float best = -3.4e38f;
    int bi = 0x7fffffff, bq = 0;
#pragma unroll
    for (int q = 0; q < NSPLIT; ++q) {
      if (pq[q] < 6) {
        const float v = tkv[((size_t)q * N_NODES + n) * 6 + pq[q]];
        const int ix = tki[((size_t)q * N_NODES + n) * 6 + pq[q]];
        if (v > best || (v == best && ix < bi)) { best = v; bi = ix; bq = q; }
      }
    }
    fw[n * 6 + s] = best;
    fi[n * 6 + s] = bi;
#pragma unroll
    for (int q = 0; q < NSPLIT; ++q) pq[q] += (bq == q) ? 1 : 0;
  }
}

// ---------------------------------------------------------------------------
// Per-node neighbor aggregation; outputs Ub, Vb in bf16 (consumed by GEMMs).
// ---------------------------------------------------------------------------
__global__ __launch_bounds__(256) void agg_kernel(const float* __restrict__ EH,
                                                  const float* __restrict__ ET,
                                                  const float* __restrict__ fw,
                                                  const int* __restrict__ fi,
                                                  unsigned short* __restrict__ Ub,
                                                  unsigned short* __restrict__ Vb) {
  __shared__ float sNb[KNB][DH];
  __shared__ float sred[4][8];
  __shared__ float ska[8];
  const int node = blockIdx.x;
  const int tid = threadIdx.x;
  float w[KNB];
  int idx[KNB];
#pragma unroll
  for (int k = 0; k < KNB; ++k) {
    w[k] = fw[node * KNB + k];
    idx[k] = fi[node * KNB + k];
  }
  float mx = w[0];
#pragma unroll
  for (int k = 1; k < KNB; ++k) mx = fmaxf(mx, w[k]);
  float pk[KNB];
  float se = 0.f;
#pragma unroll
  for (int k = 0; k < KNB; ++k) { pk[k] = expf(w[k] - mx); se += pk[k]; }
  const float inv_se = 1.f / se;
#pragma unroll
  for (int k = 0; k < KNB; ++k) pk[k] *= inv_se;
  for (int e = tid; e < KNB * DH; e += 256) {
    int k = e >> 9, d = e & 511;
    sNb[k][d] = ET[(size_t)idx[k] * DH + d];
  }
  __syncthreads();
  float eh[2];
  eh[0] = EH[(size_t)node * DH + tid];
  eh[1] = EH[(size_t)node * DH + tid + 256];
  float ka[KNB] = {0, 0, 0, 0, 0, 0};
#pragma unroll
  for (int t = 0; t < 2; ++t) {
    const int d = tid + t * 256;
    const float e_ = eh[t];
#pragma unroll
    for (int k = 0; k < KNB; ++k) {
      float Nb = sNb[k][d];
      float ehr = pk[k] * Nb + (1.f - pk[k]) * e_;
      float g = tanhf(e_ + ehr);
      ka[k] = fmaf(Nb, g, ka[k]);
    }
  }
#pragma unroll
  for (int k = 0; k < KNB; ++k) {
    float v = ka[k];
#pragma unroll
    for (int off = 32; off > 0; off >>= 1) v += __shfl_down(v, off, 64);
    if ((tid & 63) == 0) sred[tid >> 6][k] = v;
  }
  __syncthreads();
  if (tid < KNB) ska[tid] = sred[0][tid] + sred[1][tid] + sred[2][tid] + sred[3][tid];
  __syncthreads();
  float kav[KNB];
#pragma unroll
  for (int k = 0; k < KNB; ++k) kav[k] = ska[k];
  float kmx = kav[0];
#pragma unroll
  for (int k = 1; k < KNB; ++k) kmx = fmaxf(kmx, kav[k]);
  float kp[KNB];
  float ks = 0.f;
#pragma unroll
  for (int k = 0; k < KNB; ++k) { kp[k] = expf(kav[k] - kmx); ks += kp[k]; }
  const float inv_ks = 1.f / ks;
#pragma unroll
  for (int k = 0; k < KNB; ++k) kp[k] *= inv_ks;
#pragma unroll
  for (int t = 0; t < 2; ++t) {
    const int d = tid + t * 256;
    float eNh = 0.f;
#pragma unroll
    for (int k = 0; k < KNB; ++k) eNh = fmaf(kp[k], sNb[k][d], eNh);
    const float e_ = eh[t];
    Ub[(size_t)node * DH + d] = f2bf(e_ + eNh);
    Vb[(size_t)node * DH + d] = f2bf(e_ * eNh);
  }
}

// a[n] = dot(hid_bf16[n], att2_w) + att2_b ; one wave per node
__global__ __launch_bounds__(256) void att_dot(const unsigned short* __restrict__ HIDb,
                                               const float* __restrict__ w2,
                                               const float* __restrict__ b2,
                                               float* __restrict__ a) {
  const int wid = threadIdx.x >> 6, lane = threadIdx.x & 63;
  const int node = blockIdx.x * 4 + wid;
  const ushort4 h4 = *reinterpret_cast<const ushort4*>(HIDb + (size_t)node * 256 + lane * 4);
  const float4 w4 = *reinterpret_cast<const float4*>(w2 + lane * 4);
  float s = bf2f(h4.x) * w4.x + bf2f(h4.y) * w4.y + bf2f(h4.z) * w4.z + bf2f(h4.w) * w4.w;
#pragma unroll
  for (int off = 32; off > 0; off >>= 1) s += __shfl_down(s, off, 64);
  if (lane == 0) a[node] = s + b2[0];
}

// global softmax stats over a[8192]
__global__ __launch_bounds__(1024) void softmax_stats(const float* __restrict__ a,
                                                      float* __restrict__ st) {
  __shared__ float red[16];
  __shared__ float bc;
  const int tid = threadIdx.x;
  float mx = -3.4e38f;
  for (int i = tid; i < N_NODES; i += 1024) mx = fmaxf(mx, a[i]);
#pragma unroll
  for (int off = 32; off > 0; off >>= 1) mx = fmaxf(mx, __shfl_xor(mx, off, 64));
  if ((tid & 63) == 0) red[tid >> 6] = mx;
  __syncthreads();
  if (tid == 0) {
    float m = red[0];
    for (int i = 1; i < 16; ++i) m = fmaxf(m, red[i]);
    bc = m;
  }
  __syncthreads();
  const float gm = bc;
  float se = 0.f;
  for (int i = tid; i < N_NODES; i += 1024) se += expf(a[i] - gm);
#pragma unroll
  for (int off = 32; off > 0; off >>= 1) se += __shfl_xor(se, off, 64);
  if ((tid & 63) == 0) red[tid >> 6] = se;
  __syncthreads();
  if (tid == 0) {
    float s = 0.f;
    for (int i = 0; i < 16; ++i) s += red[i];
    st[0] = gm;
    st[1] = s;
  }
}

// h[c] = sum_n softmax(a)_n * emb_bf16[n][c]
__global__ __launch_bounds__(256) void readout(const unsigned short* __restrict__ EMBb,
                                               const float* __restrict__ a,
                                               const float* __restrict__ st,
                                               float* __restrict__ h) {
  __shared__ float sacc[4][64];
  const int tid = threadIdx.x;
  const int c = (blockIdx.x << 6) + (tid & 63);
  const int rsub = tid >> 6;
  const float mx = st[0], inv_se = 1.f / st[1];
  const int r0 = blockIdx.y << 8;
  float acc = 0.f;
  for (int i = 0; i < 64; ++i) {
    const int r = r0 + (i << 2) + rsub;
    const float g = expf(a[r] - mx);
    acc = fmaf(g, bf2f(EMBb[(size_t)r * DH + c]), acc);
  }
  sacc[rsub][tid & 63] = acc * inv_se;
  __syncthreads();
  if (rsub == 0) {
    float t = sacc[0][tid] + sacc[1][tid] + sacc[2][tid] + sacc[3][tid];
    atomicAdd(&h[c], t);
  }
}

// layernorm + final fc -> 2 logits
__global__ __launch_bounds__(512) void finalize(const float* __restrict__ h,
                                                const float* __restrict__ ln_g,
                                                const float* __restrict__ ln_b,
                                                const float* __restrict__ fc_w,
                                                const float* __restrict__ fc_b,
                                                float* __restrict__ out) {
  __shared__ float red0[8];
  __shared__ float red1[8];
  __shared__ float bc[2];
  const int tid = threadIdx.x;
  const int wid = tid >> 6, lane = tid & 63;
  const float v = h[tid];
  float s = v;
#pragma unroll
  for (int off = 32; off > 0; off >>= 1) s += __shfl_xor(s, off, 64);
  if (lane == 0) red0[wid] = s;
  __syncthreads();
  if (tid == 0) {
    float t = 0.f;
    for (int i = 0; i < 8; ++i) t += red0[i];
    bc[0] = t * (1.f / 512.f);
  }
  __syncthreads();
  const float mu = bc[0];
  const float dv = v - mu;
  s = dv * dv;
#pragma unroll
  for (int off = 32; off > 0; off >>= 1) s += __shfl_xor(s, off, 64);
  if (lane == 0) red0[wid] = s;
  __syncthreads();
  if (tid == 0) {
    float t = 0.f;
    for (int i = 0; i < 8; ++i) t += red0[i];
    bc[1] = t * (1.f / 512.f);
  }
  __syncthreads();
  const float var = bc[1];
  const float hn = dv / sqrtf(var + 1e-5f) * ln_g[tid] + ln_b[tid];
  float l0 = hn * fc_w[tid * 2 + 0];
  float l1 = hn * fc_w[tid * 2 + 1];
#pragma unroll
  for (int off = 32; off > 0; off >>= 1) {
    l0 += __shfl_xor(l0, off, 64);
    l1 += __shfl_xor(l1, off, 64);
  }
  if (lane == 0) { red0[wid] = l0; red1[wid] = l1; }
  __syncthreads();
  if (tid == 0) {
    float t0 = 0.f, t1 = 0.f;
    for (int i = 0; i < 8; ++i) { t0 += red0[i]; t1 += red1[i]; }
    out[0] = t0 + fc_b[0];
    out[1] = t1 + fc_b[1];
  }
}

// ---------------------------------------------------------------------------
extern "C" void kernel_launch(void* const* d_in, const int* in_sizes, int n_in,
                              void* d_out, int out_size, void* d_ws, size_t ws_size,
                              hipStream_t stream) {
  const float* x_s    = (const float*)d_in[0];
  const float* fc1_w  = (const float*)d_in[1];
  const float* fc1_b  = (const float*)d_in[2];
  const float* wh_w   = (const float*)d_in[3];
  const float* wh_b   = (const float*)d_in[4];
  const float* wt_w   = (const float*)d_in[5];
  const float* wt_b   = (const float*)d_in[6];
  const float* l1_w   = (const float*)d_in[7];
  const float* l1_b   = (const float*)d_in[8];
  const float* l2_w   = (const float*)d_in[9];
  const float* l2_b   = (const float*)d_in[10];
  const float* att1_w = (const float*)d_in[11];
  const float* att1_b = (const float*)d_in[12];
  const float* att2_w = (const float*)d_in[13];
  const float* att2_b = (const float*)d_in[14];
  const float* ln_g   = (const float*)d_in[15];
  const float* ln_b   = (const float*)d_in[16];
  const float* fc_w   = (const float*)d_in[17];
  const float* fc_b   = (const float*)d_in[18];

  float* ws = (float*)d_ws;
  const size_t BIG = (size_t)N_NODES * DH;  // 4,194,304
  // fp32: B1 (x -> e_h -> l1 partial), B2 (e_t)
  float* B1 = ws;
  float* B2 = ws + BIG;
  // bf16 pools, BIG ushorts each
  unsigned short* R1 = (unsigned short*)(ws + 2 * BIG);  // xsb -> EHb -> Ub -> hidb
  unsigned short* R2 = R1 + BIG;                          // xb -> Vb
  unsigned short* R3 = R2 + BIG;                          // ETb -> embb
  unsigned short* WT = R3 + BIG;                          // transposed bf16 weights
  float* tail = (float*)(WT + 1376256);
  float* tkv    = tail;                          // 4*8192*6
  int*   tki    = (int*)(tkv + NSPLIT * N_NODES * 6);
  float* fwv    = (float*)(tki + NSPLIT * N_NODES * 6);
  int*   fiv    = (int*)(fwv + N_NODES * 6);
  float* colsum = (float*)(fiv + N_NODES * 6);
  float* av     = colsum + DH;
  float* stats  = av + N_NODES;
  float* hbuf   = stats + 16;

  unsigned short* fc1t  = WT + 0;
  unsigned short* wht   = WT + 196608;
  unsigned short* wtt   = WT + 458752;
  unsigned short* l1t   = WT + 720896;
  unsigned short* l2t   = WT + 983040;
  unsigned short* att1t = WT + 1245184;

  const float kscale = 0.044194173824159216f;  // 512^-0.5

  // 0. prep: weight transpose+convert, x_s convert
  prep_weights<<<5376, 256, 0, stream>>>(fc1_w, wh_w, wt_w, l1_w, l2_w, att1_w, WT);
  convert_xs<<<3072, 256, 0, stream>>>(x_s, R1);  // xsb
  // 1. x = lrelu(xsb @ fc1t^T + b) -> B1 (fp32)
  gemm_bf16<1, 0, 1, 0><<<dim3(8, 128), 256, 0, stream>>>(
      R1, fc1t, fc1_b, B1, nullptr, 1.f, N_NODES, DIN, DH);
  // 2. mean-mix -> B1 fp32 + xb bf16 (R2)
  hipMemsetAsync(colsum, 0, DH * sizeof(float), stream);
  colsum_kernel<<<64, 256, 0, stream>>>(B1, colsum);
  mix_kernel<<<4096, 256, 0, stream>>>(B1, colsum, R2);
  // 3. e_h -> B1 fp32 + EHb scaled bf16 (R1); e_t -> B2 fp32 + ETb bf16 (R3)
  gemm_bf16<0, 0, 1, 1><<<dim3(8, 128), 256, 0, stream>>>(
      R2, wht, wh_b, B1, R1, kscale, N_NODES, DH, DH);
  gemm_bf16<0, 0, 1, 1><<<dim3(8, 128), 256, 0, stream>>>(
      R2, wtt, wt_b, B2, R3, 1.f, N_NODES, DH, DH);
  // 4. MFMA scoring + streaming top-6 (4 j-splits), merge
  score_topk_mfma<<<dim3(NSPLIT, 256), 256, 0, stream>>>(R1, R3, tkv, tki);
  merge_topk4<<<32, 256, 0, stream>>>(tkv, tki, fwv, fiv);
  // 5. neighbor aggregation -> Ub (R1), Vb (R2)
  agg_kernel<<<N_NODES, 256, 0, stream>>>(B1, B2, fwv, fiv, R1, R2);
  // 6. emb = lrelu(Ub@l1+b1) + lrelu(Vb@l2+b2): partial fp32 in B1, final bf16 embb (R3)
  gemm_bf16<1, 0, 1, 0><<<dim3(8, 128), 256, 0, stream>>>(
      R1, l1t, l1_b, B1, nullptr, 1.f, N_NODES, DH, DH);
  gemm_bf16<1, 1, 0, 1><<<dim3(8, 128), 256, 0, stream>>>(
      R2, l2t, l2_b, B1, R3, 1.f, N_NODES, DH, DH);
  // 7. attention readout: hid = lrelu(embb@att1+b) -> hidb bf16 (R1)
  gemm_bf16<1, 0, 0, 1><<<dim3(4, 128), 256, 0, stream>>>(
      R3, att1t, att1_b, B2, R1, 1.f, N_NODES, DH, 256);
  att_dot<<<2048, 256, 0, stream>>>(R1, att2_w, att2_b, av);
  softmax_stats<<<1, 1024, 0, stream>>>(av, stats);
  hipMemsetAsync(hbuf, 0, DH * sizeof(float), stream);
  readout<<<dim3(8, 32), 256, 0, stream>>>(R3, av, stats, hbuf);
  // 8. layernorm + logits
  finalize<<<1, 512, 0, stream>>>(hbuf, ln_g, ln_b, fc_w, fc_b, (float*)d_out);
}

// Round 5
// 443.229 us; speedup vs baseline: 4.9166x; 1.3262x over previous
//
#include <hip/hip_runtime.h>
#include <hip/hip_bf16.h>
#include <math.h>

#define N_NODES 8192
#define DIN 384
#define DH 512
#define KNB 6
#define NEG_SLOPE 0.01f
#define NSPLIT 4

typedef __attribute__((ext_vector_type(8))) short bf16x8;
typedef __attribute__((ext_vector_type(4))) float f32x4;

__device__ __forceinline__ unsigned short f2bf(float x) {
  unsigned int u = __float_as_uint(x);
  unsigned int r = (u + 0x7fffu + ((u >> 16) & 1u)) >> 16;  // RNE
  return (unsigned short)r;
}
__device__ __forceinline__ float bf2f(unsigned short u) {
  return __uint_as_float(((unsigned int)u) << 16);
}

// ---------------------------------------------------------------------------
// Weight prep: W[K][N] fp32 -> Wt[N][K] bf16, all 6 weights into one pool.
// ---------------------------------------------------------------------------
__global__ __launch_bounds__(256) void prep_weights(
    const float* __restrict__ w0, const float* __restrict__ w1,
    const float* __restrict__ w2, const float* __restrict__ w3,
    const float* __restrict__ w4, const float* __restrict__ w5,
    unsigned short* __restrict__ pool) {
  const int f = blockIdx.x * 256 + threadIdx.x;
  const int E0 = 196608, E1 = 458752, E2 = 720896, E3 = 983040, E4 = 1245184, E5 = 1376256;
  if (f >= E5) return;
  const float* src; int off, Kw, Nw;
  if (f < E0)      { src = w0; off = 0;  Kw = 384; Nw = 512; }
  else if (f < E1) { src = w1; off = E0; Kw = 512; Nw = 512; }
  else if (f < E2) { src = w2; off = E1; Kw = 512; Nw = 512; }
  else if (f < E3) { src = w3; off = E2; Kw = 512; Nw = 512; }
  else if (f < E4) { src = w4; off = E3; Kw = 512; Nw = 512; }
  else             { src = w5; off = E4; Kw = 512; Nw = 256; }
  const int local = f - off;
  const int n = local / Kw, k = local - n * Kw;
  pool[f] = f2bf(src[(size_t)k * Nw + n]);
}

// x_s fp32 -> bf16
__global__ __launch_bounds__(256) void convert_xs(const float* __restrict__ xs,
                                                  unsigned short* __restrict__ out) {
  const size_t i = ((size_t)blockIdx.x * 256 + threadIdx.x) * 4;
  const float4 v = *reinterpret_cast<const float4*>(xs + i);
  ushort4 o;
  o.x = f2bf(v.x); o.y = f2bf(v.y); o.z = f2bf(v.z); o.w = f2bf(v.w);
  *reinterpret_cast<ushort4*>(out + i) = o;
}

// ---------------------------------------------------------------------------
// bf16 MFMA GEMM: C[M,N] = act(A[M,K]bf16 @ Wt[N,K]bf16^T + bias) variants.
// ---------------------------------------------------------------------------
template <int ACT, int ACC, int WF32, int WBF16>
__global__ __launch_bounds__(256) void gemm_bf16(
    const unsigned short* __restrict__ A, const unsigned short* __restrict__ Wt,
    const float* __restrict__ bias, float* __restrict__ C,
    unsigned short* __restrict__ Cb, float bscale, int M, int K, int N) {
  __shared__ unsigned short sa[64 * 64];
  __shared__ unsigned short sb[64 * 64];
  const int tid = threadIdx.x;
  const int wave = tid >> 6, lane = tid & 63;
  const int lo16 = lane & 15, hi = lane >> 4;
  const int row0 = blockIdx.y << 6, col0 = blockIdx.x << 6;
  f32x4 acc[4];
#pragma unroll
  for (int rt = 0; rt < 4; ++rt) { acc[rt].x = 0.f; acc[rt].y = 0.f; acc[rt].z = 0.f; acc[rt].w = 0.f; }
  for (int k0 = 0; k0 < K; k0 += 64) {
    __syncthreads();
#pragma unroll
    for (int i = 0; i < 2; ++i) {
      const int c = i * 256 + tid;
      const int r = c >> 3, i8 = c & 7;
      const bf16x8 va = *reinterpret_cast<const bf16x8*>(A + (size_t)(row0 + r) * K + k0 + i8 * 8);
      const bf16x8 vb = *reinterpret_cast<const bf16x8*>(Wt + (size_t)(col0 + r) * K + k0 + i8 * 8);
      const int byte = r * 128 + ((i8 * 16) ^ ((r & 7) << 4));
      *reinterpret_cast<bf16x8*>(reinterpret_cast<char*>(sa) + byte) = va;
      *reinterpret_cast<bf16x8*>(reinterpret_cast<char*>(sb) + byte) = vb;
    }
    __syncthreads();
#pragma unroll
    for (int kk2 = 0; kk2 < 2; ++kk2) {
      const int col = wave * 16 + lo16;
      const int bbyte = col * 128 + (((kk2 << 6) + (hi << 4)) ^ ((col & 7) << 4));
      const bf16x8 bf = *reinterpret_cast<const bf16x8*>(reinterpret_cast<const char*>(sb) + bbyte);
#pragma unroll
      for (int rt = 0; rt < 4; ++rt) {
        const int row = rt * 16 + lo16;
        const int abyte = row * 128 + (((kk2 << 6) + (hi << 4)) ^ ((row & 7) << 4));
        const bf16x8 af = *reinterpret_cast<const bf16x8*>(reinterpret_cast<const char*>(sa) + abyte);
        acc[rt] = __builtin_amdgcn_mfma_f32_16x16x32_bf16(af, bf, acc[rt], 0, 0, 0);
      }
    }
  }
  const int col = col0 + wave * 16 + lo16;
  const float bv = bias[col];
#pragma unroll
  for (int rt = 0; rt < 4; ++rt) {
#pragma unroll
    for (int j = 0; j < 4; ++j) {
      const int r = row0 + rt * 16 + hi * 4 + j;
      float v = acc[rt][j] + bv;
      if (ACT) v = v > 0.f ? v : NEG_SLOPE * v;
      if (ACC) v += C[(size_t)r * N + col];
      if (WF32) C[(size_t)r * N + col] = v;
      if (WBF16) Cb[(size_t)r * N + col] = f2bf(v * bscale);
    }
  }
}

// ---------------------------------------------------------------------------
// Column sums of X[8192 x 512]
// ---------------------------------------------------------------------------
__global__ __launch_bounds__(256) void colsum_kernel(const float* __restrict__ X,
                                                     float* __restrict__ cs) {
  const int tid = threadIdx.x;
  float s0 = 0.f, s1 = 0.f;
  const int r0 = blockIdx.x * 128;
  for (int r = r0; r < r0 + 128; ++r) {
    s0 += X[(size_t)r * DH + tid];
    s1 += X[(size_t)r * DH + tid + 256];
  }
  atomicAdd(&cs[tid], s0);
  atomicAdd(&cs[tid + 256], s1);
}

// x = (x + colmean) * 0.5 ; also emit bf16 copy
__global__ __launch_bounds__(256) void mix_kernel(float* __restrict__ X,
                                                  const float* __restrict__ cs,
                                                  unsigned short* __restrict__ Xb) {
  const size_t gid = (size_t)blockIdx.x * 256 + threadIdx.x;
  const int c4 = ((int)gid & 127) << 2;
  float4 x = *reinterpret_cast<float4*>(X + gid * 4);
  const float inv = 1.f / 8192.f;
  x.x = (x.x + cs[c4 + 0] * inv) * 0.5f;
  x.y = (x.y + cs[c4 + 1] * inv) * 0.5f;
  x.z = (x.z + cs[c4 + 2] * inv) * 0.5f;
  x.w = (x.w + cs[c4 + 3] * inv) * 0.5f;
  *reinterpret_cast<float4*>(X + gid * 4) = x;
  ushort4 o;
  o.x = f2bf(x.x); o.y = f2bf(x.y); o.z = f2bf(x.z); o.w = f2bf(x.w);
  *reinterpret_cast<ushort4*>(Xb + gid * 4) = o;
}

// ---------------------------------------------------------------------------
// MFMA scoring + streaming top-6, v3 ("big-R"):
// 256 blocks x 512 thr (8 waves). Block = 128 rows x 2048-col split.
// A (128x512) staged ONCE in XOR-swizzled LDS (128 KB), shared by all waves:
// per kk, 8 ds_read_b128 feed 32 MFMAs (4 col-frags reuse). B per-lane from
// global (2 MB strip per XCD-pair, L2-resident via bid->split decode).
// Scores scanned via per-wave LDS slices (64 rows x 8 cols, 16 passes/jt);
// each lane keeps top-6 for rows {lane, 64+lane}; 8-wave merge at end.
// ET L2/L3 traffic: 512 MB total (was 2 GB at R=32).
// ---------------------------------------------------------------------------
__global__ __launch_bounds__(512, 2) void score_topk_v3(
    const unsigned short* __restrict__ EHb, const unsigned short* __restrict__ ETb,
    float* __restrict__ tkv, int* __restrict__ tki) {
  __shared__ unsigned short sa[128 * 512];  // 131072 B, swizzled A
  __shared__ float swb[8][8 * 68];          // 17408 B, per-wave score slices
  const int tid = threadIdx.x;
  const int wave = tid >> 6, lane = tid & 63;
  const int lo16 = lane & 15, hi = lane >> 4;
  // bid decode: XCD-pair (bid&7)>>1 owns one col-split strip (2MB, L2-fit)
  const int bid = blockIdx.x;
  const int split = (bid & 7) >> 1;
  const int rowblk = ((bid >> 3) << 1) | (bid & 1);
  const int grow0 = rowblk << 7;       // 128 rows/block
  const int colbase0 = split << 11;    // 2048 cols/split

  // stage A rows [grow0, grow0+128) swizzled: thread loads 16 x 16B chunks
#pragma unroll
  for (int i = 0; i < 16; ++i) {
    const int c = i * 512 + tid;           // 0..8191 chunks
    const int row = c >> 6, i8 = c & 63;
    const bf16x8 v = *reinterpret_cast<const bf16x8*>(
        EHb + (size_t)(grow0 + row) * DH + i8 * 8);
    const int byte = row * 1024 + ((i8 * 16) ^ ((row & 7) << 4));
    *reinterpret_cast<bf16x8*>(reinterpret_cast<char*>(sa) + byte) = v;
  }
  __syncthreads();

  float tv[2][6];
  int ti[2][6];
#pragma unroll
  for (int a = 0; a < 2; ++a)
#pragma unroll
    for (int s = 0; s < 6; ++s) { tv[a][s] = -3.4e38f; ti[a][s] = 0; }

  float* sw = swb[wave];

  for (int jt = 0; jt < 4; ++jt) {
    const int wcol0 = colbase0 + jt * 512 + wave * 64;
    f32x4 acc[8][4];
#pragma unroll
    for (int rt = 0; rt < 8; ++rt)
#pragma unroll
      for (int ct = 0; ct < 4; ++ct) {
        acc[rt][ct].x = 0.f; acc[rt][ct].y = 0.f; acc[rt][ct].z = 0.f; acc[rt][ct].w = 0.f;
      }
    bf16x8 bcur[4];
#pragma unroll
    for (int ct = 0; ct < 4; ++ct)
      bcur[ct] = *reinterpret_cast<const bf16x8*>(
          ETb + (size_t)(wcol0 + ct * 16 + lo16) * DH + hi * 8);
#pragma unroll
    for (int kk = 0; kk < 16; ++kk) {
      const int kn = (kk + 1) & 15;  // kk=15 harmlessly reloads kk=0
      bf16x8 bnxt[4];
#pragma unroll
      for (int ct = 0; ct < 4; ++ct)
        bnxt[ct] = *reinterpret_cast<const bf16x8*>(
            ETb + (size_t)(wcol0 + ct * 16 + lo16) * DH + kn * 32 + hi * 8);
      const int inner = (kk << 6) + (hi << 4);
#pragma unroll
      for (int rt = 0; rt < 8; ++rt) {
        const int row = rt * 16 + lo16;
        const bf16x8 af = *reinterpret_cast<const bf16x8*>(
            reinterpret_cast<const char*>(sa) + row * 1024 + (inner ^ ((row & 7) << 4)));
#pragma unroll
        for (int ct = 0; ct < 4; ++ct)
          acc[rt][ct] = __builtin_amdgcn_mfma_f32_16x16x32_bf16(af, bcur[ct], acc[rt][ct], 0, 0, 0);
      }
#pragma unroll
      for (int ct = 0; ct < 4; ++ct) bcur[ct] = bnxt[ct];
    }
    // dump/scan: 16 passes of (a row-half, ct, h col-half of frag)
#pragma unroll
    for (int a = 0; a < 2; ++a) {
#pragma unroll
      for (int ct = 0; ct < 4; ++ct) {
#pragma unroll
        for (int h = 0; h < 2; ++h) {
          if ((lo16 >> 3) == h) {
#pragma unroll
            for (int rtl = 0; rtl < 4; ++rtl)
              *reinterpret_cast<f32x4*>(sw + (lo16 & 7) * 68 + rtl * 16 + hi * 4) =
                  acc[a * 4 + rtl][ct];
          }
          asm volatile("s_waitcnt lgkmcnt(0)" ::: "memory");
#pragma unroll
          for (int cc = 0; cc < 8; ++cc) {
            const float v = sw[cc * 68 + lane];
            const int col = wcol0 + ct * 16 + h * 8 + cc;
            if (v > tv[a][5]) {
              tv[a][5] = v; ti[a][5] = col;
#pragma unroll
              for (int p = 5; p > 0; --p) {
                if (tv[a][p] > tv[a][p - 1]) {
                  float tvt = tv[a][p]; tv[a][p] = tv[a][p - 1]; tv[a][p - 1] = tvt;
                  int tit = ti[a][p]; ti[a][p] = ti[a][p - 1]; ti[a][p - 1] = tit;
                }
              }
            }
          }
          asm volatile("s_waitcnt lgkmcnt(0)" ::: "memory");
        }
      }
    }
  }
  __syncthreads();
  // merge: reuse A region. mv[128 rows][8 waves][6] + mi
  float* mv = reinterpret_cast<float*>(sa);
  int* mi = reinterpret_cast<int*>(mv + 128 * 8 * 6);
#pragma unroll
  for (int a = 0; a < 2; ++a) {
    const int row = a * 64 + lane;
#pragma unroll
    for (int s = 0; s < 6; ++s) {
      mv[(row * 8 + wave) * 6 + s] = tv[a][s];
      mi[(row * 8 + wave) * 6 + s] = ti[a][s];
    }
  }
  __syncthreads();
  if (tid < 128) {
    int pq[8] = {0, 0, 0, 0, 0, 0, 0, 0};
    const int base = (split * N_NODES + grow0 + tid) * 6;
    for (int s = 0; s < 6; ++s) {
      float best = -3.4e38f;
      int bi = 0x7fffffff, bq = 0;
#pragma unroll
      for (int q = 0; q < 8; ++q) {
        if (pq[q] < 6) {
          const float v = mv[(tid * 8 + q) * 6 + pq[q]];
          const int ix = mi[(tid * 8 + q) * 6 + pq[q]];
          if (v > best || (v == best && ix < bi)) { best = v; bi = ix; bq = q; }
        }
      }
      tkv[base + s] = best;
      tki[base + s] = bi;
#pragma unroll
      for (int q = 0; q < 8; ++q) pq[q] += (bq == q) ? 1 : 0;
    }
  }
}

// merge the 4 j-split top-6 lists into final top-6
__global__ __launch_bounds__(256) void merge_topk4(const float* __restrict__ tkv,
                                                   const int* __restrict__ tki,
                                                   float* __restrict__ fw,
                                                   int* __restrict__ fi) {
  const int n = blockIdx.x * 256 + threadIdx.x;
  int pq[NSPLIT] = {0, 0, 0, 0};
  for (int s = 0; s < 6; ++s) {
    float best = -3.4e38f;
    int bi = 0x7fffffff, bq = 0;
#pragma unroll
    for (int q = 0; q < NSPLIT; ++q) {
      if (pq[q] < 6) {
        const float v = tkv[((size_t)q * N_NODES + n) * 6 + pq[q]];
        const int ix = tki[((size_t)q * N_NODES + n) * 6 + pq[q]];
        if (v > best || (v == best && ix < bi)) { best = v; bi = ix; bq = q; }
      }
    }
    fw[n * 6 + s] = best;
    fi[n * 6 + s] = bi;
#pragma unroll
    for (int q = 0; q < NSPLIT; ++q) pq[q] += (bq == q) ? 1 : 0;
  }
}

// ---------------------------------------------------------------------------
// Per-node neighbor aggregation; outputs Ub, Vb in bf16.
// ---------------------------------------------------------------------------
__global__ __launch_bounds__(256) void agg_kernel(const float* __restrict__ EH,
                                                  const float* __restrict__ ET,
                                                  const float* __restrict__ fw,
                                                  const int* __restrict__ fi,
                                                  unsigned short* __restrict__ Ub,
                                                  unsigned short* __restrict__ Vb) {
  __shared__ float sNb[KNB][DH];
  __shared__ float sred[4][8];
  __shared__ float ska[8];
  const int node = blockIdx.x;
  const int tid = threadIdx.x;
  float w[KNB];
  int idx[KNB];
#pragma unroll
  for (int k = 0; k < KNB; ++k) {
    w[k] = fw[node * KNB + k];
    idx[k] = fi[node * KNB + k];
  }
  float mx = w[0];
#pragma unroll
  for (int k = 1; k < KNB; ++k) mx = fmaxf(mx, w[k]);
  float pk[KNB];
  float se = 0.f;
#pragma unroll
  for (int k = 0; k < KNB; ++k) { pk[k] = expf(w[k] - mx); se += pk[k]; }
  const float inv_se = 1.f / se;
#pragma unroll
  for (int k = 0; k < KNB; ++k) pk[k] *= inv_se;
  for (int e = tid; e < KNB * DH; e += 256) {
    int k = e >> 9, d = e & 511;
    sNb[k][d] = ET[(size_t)idx[k] * DH + d];
  }
  __syncthreads();
  float eh[2];
  eh[0] = EH[(size_t)node * DH + tid];
  eh[1] = EH[(size_t)node * DH + tid + 256];
  float ka[KNB] = {0, 0, 0, 0, 0, 0};
#pragma unroll
  for (int t = 0; t < 2; ++t) {
    const int d = tid + t * 256;
    const float e_ = eh[t];
#pragma unroll
    for (int k = 0; k < KNB; ++k) {
      float Nb = sNb[k][d];
      float ehr = pk[k] * Nb + (1.f - pk[k]) * e_;
      float g = tanhf(e_ + ehr);
      ka[k] = fmaf(Nb, g, ka[k]);
    }
  }
#pragma unroll
  for (int k = 0; k < KNB; ++k) {
    float v = ka[k];
#pragma unroll
    for (int off = 32; off > 0; off >>= 1) v += __shfl_down(v, off, 64);
    if ((tid & 63) == 0) sred[tid >> 6][k] = v;
  }
  __syncthreads();
  if (tid < KNB) ska[tid] = sred[0][tid] + sred[1][tid] + sred[2][tid] + sred[3][tid];
  __syncthreads();
  float kav[KNB];
#pragma unroll
  for (int k = 0; k < KNB; ++k) kav[k] = ska[k];
  float kmx = kav[0];
#pragma unroll
  for (int k = 1; k < KNB; ++k) kmx = fmaxf(kmx, kav[k]);
  float kp[KNB];
  float ks = 0.f;
#pragma unroll
  for (int k = 0; k < KNB; ++k) { kp[k] = expf(kav[k] - kmx); ks += kp[k]; }
  const float inv_ks = 1.f / ks;
#pragma unroll
  for (int k = 0; k < KNB; ++k) kp[k] *= inv_ks;
#pragma unroll
  for (int t = 0; t < 2; ++t) {
    const int d = tid + t * 256;
    float eNh = 0.f;
#pragma unroll
    for (int k = 0; k < KNB; ++k) eNh = fmaf(kp[k], sNb[k][d], eNh);
    const float e_ = eh[t];
    Ub[(size_t)node * DH + d] = f2bf(e_ + eNh);
    Vb[(size_t)node * DH + d] = f2bf(e_ * eNh);
  }
}

// a[n] = dot(hid_bf16[n], att2_w) + att2_b ; one wave per node
__global__ __launch_bounds__(256) void att_dot(const unsigned short* __restrict__ HIDb,
                                               const float* __restrict__ w2,
                                               const float* __restrict__ b2,
                                               float* __restrict__ a) {
  const int wid = threadIdx.x >> 6, lane = threadIdx.x & 63;
  const int node = blockIdx.x * 4 + wid;
  const ushort4 h4 = *reinterpret_cast<const ushort4*>(HIDb + (size_t)node * 256 + lane * 4);
  const float4 w4 = *reinterpret_cast<const float4*>(w2 + lane * 4);
  float s = bf2f(h4.x) * w4.x + bf2f(h4.y) * w4.y + bf2f(h4.z) * w4.z + bf2f(h4.w) * w4.w;
#pragma unroll
  for (int off = 32; off > 0; off >>= 1) s += __shfl_down(s, off, 64);
  if (lane == 0) a[node] = s + b2[0];
}

// global softmax stats over a[8192]
__global__ __launch_bounds__(1024) void softmax_stats(const float* __restrict__ a,
                                                      float* __restrict__ st) {
  __shared__ float red[16];
  __shared__ float bc;
  const int tid = threadIdx.x;
  float mx = -3.4e38f;
  for (int i = tid; i < N_NODES; i += 1024) mx = fmaxf(mx, a[i]);
#pragma unroll
  for (int off = 32; off > 0; off >>= 1) mx = fmaxf(mx, __shfl_xor(mx, off, 64));
  if ((tid & 63) == 0) red[tid >> 6] = mx;
  __syncthreads();
  if (tid == 0) {
    float m = red[0];
    for (int i = 1; i < 16; ++i) m = fmaxf(m, red[i]);
    bc = m;
  }
  __syncthreads();
  const float gm = bc;
  float se = 0.f;
  for (int i = tid; i < N_NODES; i += 1024) se += expf(a[i] - gm);
#pragma unroll
  for (int off = 32; off > 0; off >>= 1) se += __shfl_xor(se, off, 64);
  if ((tid & 63) == 0) red[tid >> 6] = se;
  __syncthreads();
  if (tid == 0) {
    float s = 0.f;
    for (int i = 0; i < 16; ++i) s += red[i];
    st[0] = gm;
    st[1] = s;
  }
}

// h[c] = sum_n softmax(a)_n * emb_bf16[n][c]
__global__ __launch_bounds__(256) void readout(const unsigned short* __restrict__ EMBb,
                                               const float* __restrict__ a,
                                               const float* __restrict__ st,
                                               float* __restrict__ h) {
  __shared__ float sacc[4][64];
  const int tid = threadIdx.x;
  const int c = (blockIdx.x << 6) + (tid & 63);
  const int rsub = tid >> 6;
  const float mx = st[0], inv_se = 1.f / st[1];
  const int r0 = blockIdx.y << 8;
  float acc = 0.f;
  for (int i = 0; i < 64; ++i) {
    const int r = r0 + (i << 2) + rsub;
    const float g = expf(a[r] - mx);
    acc = fmaf(g, bf2f(EMBb[(size_t)r * DH + c]), acc);
  }
  sacc[rsub][tid & 63] = acc * inv_se;
  __syncthreads();
  if (rsub == 0) {
    float t = sacc[0][tid] + sacc[1][tid] + sacc[2][tid] + sacc[3][tid];
    atomicAdd(&h[c], t);
  }
}

// layernorm + final fc -> 2 logits
__global__ __launch_bounds__(512) void finalize(const float* __restrict__ h,
                                                const float* __restrict__ ln_g,
                                                const float* __restrict__ ln_b,
                                                const float* __restrict__ fc_w,
                                                const float* __restrict__ fc_b,
                                                float* __restrict__ out) {
  __shared__ float red0[8];
  __shared__ float red1[8];
  __shared__ float bc[2];
  const int tid = threadIdx.x;
  const int wid = tid >> 6, lane = tid & 63;
  const float v = h[tid];
  float s = v;
#pragma unroll
  for (int off = 32; off > 0; off >>= 1) s += __shfl_xor(s, off, 64);
  if (lane == 0) red0[wid] = s;
  __syncthreads();
  if (tid == 0) {
    float t = 0.f;
    for (int i = 0; i < 8; ++i) t += red0[i];
    bc[0] = t * (1.f / 512.f);
  }
  __syncthreads();
  const float mu = bc[0];
  const float dv = v - mu;
  s = dv * dv;
#pragma unroll
  for (int off = 32; off > 0; off >>= 1) s += __shfl_xor(s, off, 64);
  if (lane == 0) red0[wid] = s;
  __syncthreads();
  if (tid == 0) {
    float t = 0.f;
    for (int i = 0; i < 8; ++i) t += red0[i];
    bc[1] = t * (1.f / 512.f);
  }
  __syncthreads();
  const float var = bc[1];
  const float hn = dv / sqrtf(var + 1e-5f) * ln_g[tid] + ln_b[tid];
  float l0 = hn * fc_w[tid * 2 + 0];
  float l1 = hn * fc_w[tid * 2 + 1];
#pragma unroll
  for (int off = 32; off > 0; off >>= 1) {
    l0 += __shfl_xor(l0, off, 64);
    l1 += __shfl_xor(l1, off, 64);
  }
  if (lane == 0) { red0[wid] = l0; red1[wid] = l1; }
  __syncthreads();
  if (tid == 0) {
    float t0 = 0.f, t1 = 0.f;
    for (int i = 0; i < 8; ++i) { t0 += red0[i]; t1 += red1[i]; }
    out[0] = t0 + fc_b[0];
    out[1] = t1 + fc_b[1];
  }
}

// ---------------------------------------------------------------------------
extern "C" void kernel_launch(void* const* d_in, const int* in_sizes, int n_in,
                              void* d_out, int out_size, void* d_ws, size_t ws_size,
                              hipStream_t stream) {
  const float* x_s    = (const float*)d_in[0];
  const float* fc1_w  = (const float*)d_in[1];
  const float* fc1_b  = (const float*)d_in[2];
  const float* wh_w   = (const float*)d_in[3];
  const float* wh_b   = (const float*)d_in[4];
  const float* wt_w   = (const float*)d_in[5];
  const float* wt_b   = (const float*)d_in[6];
  const float* l1_w   = (const float*)d_in[7];
  const float* l1_b   = (const float*)d_in[8];
  const float* l2_w   = (const float*)d_in[9];
  const float* l2_b   = (const float*)d_in[10];
  const float* att1_w = (const float*)d_in[11];
  const float* att1_b = (const float*)d_in[12];
  const float* att2_w = (const float*)d_in[13];
  const float* att2_b = (const float*)d_in[14];
  const float* ln_g   = (const float*)d_in[15];
  const float* ln_b   = (const float*)d_in[16];
  const float* fc_w   = (const float*)d_in[17];
  const float* fc_b   = (const float*)d_in[18];

  float* ws = (float*)d_ws;
  const size_t BIG = (size_t)N_NODES * DH;  // 4,194,304
  float* B1 = ws;
  float* B2 = ws + BIG;
  unsigned short* R1 = (unsigned short*)(ws + 2 * BIG);  // xsb -> EHb -> Ub -> hidb
  unsigned short* R2 = R1 + BIG;                          // xb -> Vb
  unsigned short* R3 = R2 + BIG;                          // ETb -> embb
  unsigned short* WT = R3 + BIG;                          // transposed bf16 weights
  float* tail = (float*)(WT + 1376256);
  float* tkv    = tail;                          // 4*8192*6
  int*   tki    = (int*)(tkv + NSPLIT * N_NODES * 6);
  float* fwv    = (float*)(tki + NSPLIT * N_NODES * 6);
  int*   fiv    = (int*)(fwv + N_NODES * 6);
  float* colsum = (float*)(fiv + N_NODES * 6);
  float* av     = colsum + DH;
  float* stats  = av + N_NODES;
  float* hbuf   = stats + 16;

  unsigned short* fc1t  = WT + 0;
  unsigned short* wht   = WT + 196608;
  unsigned short* wtt   = WT + 458752;
  unsigned short* l1t   = WT + 720896;
  unsigned short* l2t   = WT + 983040;
  unsigned short* att1t = WT + 1245184;

  const float kscale = 0.044194173824159216f;  // 512^-0.5

  // 0. prep
  prep_weights<<<5376, 256, 0, stream>>>(fc1_w, wh_w, wt_w, l1_w, l2_w, att1_w, WT);
  convert_xs<<<3072, 256, 0, stream>>>(x_s, R1);
  // 1. x = lrelu(xsb @ fc1t^T + b) -> B1
  gemm_bf16<1, 0, 1, 0><<<dim3(8, 128), 256, 0, stream>>>(
      R1, fc1t, fc1_b, B1, nullptr, 1.f, N_NODES, DIN, DH);
  // 2. mean-mix -> B1 fp32 + xb bf16 (R2)
  hipMemsetAsync(colsum, 0, DH * sizeof(float), stream);
  colsum_kernel<<<64, 256, 0, stream>>>(B1, colsum);
  mix_kernel<<<4096, 256, 0, stream>>>(B1, colsum, R2);
  // 3. e_h -> B1 + EHb*scale (R1); e_t -> B2 + ETb (R3)
  gemm_bf16<0, 0, 1, 1><<<dim3(8, 128), 256, 0, stream>>>(
      R2, wht, wh_b, B1, R1, kscale, N_NODES, DH, DH);
  gemm_bf16<0, 0, 1, 1><<<dim3(8, 128), 256, 0, stream>>>(
      R2, wtt, wt_b, B2, R3, 1.f, N_NODES, DH, DH);
  // 4. scoring v3 + merge
  score_topk_v3<<<256, 512, 0, stream>>>(R1, R3, tkv, tki);
  merge_topk4<<<32, 256, 0, stream>>>(tkv, tki, fwv, fiv);
  // 5. aggregation -> Ub (R1), Vb (R2)
  agg_kernel<<<N_NODES, 256, 0, stream>>>(B1, B2, fwv, fiv, R1, R2);
  // 6. emb = lrelu(Ub@l1+b1) + lrelu(Vb@l2+b2) -> B1 fp32, embb (R3)
  gemm_bf16<1, 0, 1, 0><<<dim3(8, 128), 256, 0, stream>>>(
      R1, l1t, l1_b, B1, nullptr, 1.f, N_NODES, DH, DH);
  gemm_bf16<1, 1, 0, 1><<<dim3(8, 128), 256, 0, stream>>>(
      R2, l2t, l2_b, B1, R3, 1.f, N_NODES, DH, DH);
  // 7. attention readout
  gemm_bf16<1, 0, 0, 1><<<dim3(4, 128), 256, 0, stream>>>(
      R3, att1t, att1_b, B2, R1, 1.f, N_NODES, DH, 256);
  att_dot<<<2048, 256, 0, stream>>>(R1, att2_w, att2_b, av);
  softmax_stats<<<1, 1024, 0, stream>>>(av, stats);
  hipMemsetAsync(hbuf, 0, DH * sizeof(float), stream);
  readout<<<dim3(8, 32), 256, 0, stream>>>(R3, av, stats, hbuf);
  // 8. layernorm + logits
  finalize<<<1, 512, 0, stream>>>(hbuf, ln_g, ln_b, fc_w, fc_b, (float*)d_out);
}

// Round 6
// 423.189 us; speedup vs baseline: 5.1494x; 1.0474x over previous
//
#include <hip/hip_runtime.h>
#include <hip/hip_bf16.h>
#include <math.h>

#define N_NODES 8192
#define DIN 384
#define DH 512
#define KNB 6
#define NEG_SLOPE 0.01f
#define NSPLIT 4

typedef __attribute__((ext_vector_type(8))) short bf16x8;
typedef __attribute__((ext_vector_type(4))) float f32x4;

__device__ __forceinline__ unsigned short f2bf(float x) {
  unsigned int u = __float_as_uint(x);
  unsigned int r = (u + 0x7fffu + ((u >> 16) & 1u)) >> 16;  // RNE
  return (unsigned short)r;
}
__device__ __forceinline__ float bf2f(unsigned short u) {
  return __uint_as_float(((unsigned int)u) << 16);
}

// ---------------------------------------------------------------------------
// Weight prep: W[K][N] fp32 -> Wt[N][K] bf16, all 6 weights into one pool.
// ---------------------------------------------------------------------------
__global__ __launch_bounds__(256) void prep_weights(
    const float* __restrict__ w0, const float* __restrict__ w1,
    const float* __restrict__ w2, const float* __restrict__ w3,
    const float* __restrict__ w4, const float* __restrict__ w5,
    unsigned short* __restrict__ pool) {
  const int f = blockIdx.x * 256 + threadIdx.x;
  const int E0 = 196608, E1 = 458752, E2 = 720896, E3 = 983040, E4 = 1245184, E5 = 1376256;
  if (f >= E5) return;
  const float* src; int off, Kw, Nw;
  if (f < E0)      { src = w0; off = 0;  Kw = 384; Nw = 512; }
  else if (f < E1) { src = w1; off = E0; Kw = 512; Nw = 512; }
  else if (f < E2) { src = w2; off = E1; Kw = 512; Nw = 512; }
  else if (f < E3) { src = w3; off = E2; Kw = 512; Nw = 512; }
  else if (f < E4) { src = w4; off = E3; Kw = 512; Nw = 512; }
  else             { src = w5; off = E4; Kw = 512; Nw = 256; }
  const int local = f - off;
  const int n = local / Kw, k = local - n * Kw;
  pool[f] = f2bf(src[(size_t)k * Nw + n]);
}

// x_s fp32 -> bf16
__global__ __launch_bounds__(256) void convert_xs(const float* __restrict__ xs,
                                                  unsigned short* __restrict__ out) {
  const size_t i = ((size_t)blockIdx.x * 256 + threadIdx.x) * 4;
  const float4 v = *reinterpret_cast<const float4*>(xs + i);
  ushort4 o;
  o.x = f2bf(v.x); o.y = f2bf(v.y); o.z = f2bf(v.z); o.w = f2bf(v.w);
  *reinterpret_cast<ushort4*>(out + i) = o;
}

// ---------------------------------------------------------------------------
// bf16 MFMA GEMM: C[M,N] = act(A[M,K]bf16 @ Wt[N,K]bf16^T + bias) variants.
// PACKB: bf16 output written in MFMA-fragment-major layout for score kernel:
//   Cb[(r>>4)*8192 + (c>>5)*512 + (((c&31)>>3)*16 + (r&15))*8 + (c&7)]
// (requires N==512). Same scatter cost as the row-major bf16 write.
// ---------------------------------------------------------------------------
template <int ACT, int ACC, int WF32, int WBF16, int PACKB>
__global__ __launch_bounds__(256) void gemm_bf16(
    const unsigned short* __restrict__ A, const unsigned short* __restrict__ Wt,
    const float* __restrict__ bias, float* __restrict__ C,
    unsigned short* __restrict__ Cb, float bscale, int M, int K, int N) {
  __shared__ unsigned short sa[64 * 64];
  __shared__ unsigned short sb[64 * 64];
  const int tid = threadIdx.x;
  const int wave = tid >> 6, lane = tid & 63;
  const int lo16 = lane & 15, hi = lane >> 4;
  const int row0 = blockIdx.y << 6, col0 = blockIdx.x << 6;
  f32x4 acc[4];
#pragma unroll
  for (int rt = 0; rt < 4; ++rt) { acc[rt].x = 0.f; acc[rt].y = 0.f; acc[rt].z = 0.f; acc[rt].w = 0.f; }
  for (int k0 = 0; k0 < K; k0 += 64) {
    __syncthreads();
#pragma unroll
    for (int i = 0; i < 2; ++i) {
      const int c = i * 256 + tid;
      const int r = c >> 3, i8 = c & 7;
      const bf16x8 va = *reinterpret_cast<const bf16x8*>(A + (size_t)(row0 + r) * K + k0 + i8 * 8);
      const bf16x8 vb = *reinterpret_cast<const bf16x8*>(Wt + (size_t)(col0 + r) * K + k0 + i8 * 8);
      const int byte = r * 128 + ((i8 * 16) ^ ((r & 7) << 4));
      *reinterpret_cast<bf16x8*>(reinterpret_cast<char*>(sa) + byte) = va;
      *reinterpret_cast<bf16x8*>(reinterpret_cast<char*>(sb) + byte) = vb;
    }
    __syncthreads();
#pragma unroll
    for (int kk2 = 0; kk2 < 2; ++kk2) {
      const int col = wave * 16 + lo16;
      const int bbyte = col * 128 + (((kk2 << 6) + (hi << 4)) ^ ((col & 7) << 4));
      const bf16x8 bf = *reinterpret_cast<const bf16x8*>(reinterpret_cast<const char*>(sb) + bbyte);
#pragma unroll
      for (int rt = 0; rt < 4; ++rt) {
        const int row = rt * 16 + lo16;
        const int abyte = row * 128 + (((kk2 << 6) + (hi << 4)) ^ ((row & 7) << 4));
        const bf16x8 af = *reinterpret_cast<const bf16x8*>(reinterpret_cast<const char*>(sa) + abyte);
        acc[rt] = __builtin_amdgcn_mfma_f32_16x16x32_bf16(af, bf, acc[rt], 0, 0, 0);
      }
    }
  }
  const int colg = col0 + wave * 16 + lo16;
  const float bv = bias[colg];
#pragma unroll
  for (int rt = 0; rt < 4; ++rt) {
#pragma unroll
    for (int j = 0; j < 4; ++j) {
      const int r = row0 + rt * 16 + hi * 4 + j;
      float v = acc[rt][j] + bv;
      if (ACT) v = v > 0.f ? v : NEG_SLOPE * v;
      if (ACC) v += C[(size_t)r * N + colg];
      if (WF32) C[(size_t)r * N + colg] = v;
      if (WBF16) {
        if (PACKB) {
          const size_t idx = (size_t)(r >> 4) * 8192 + (size_t)(colg >> 5) * 512 +
                             (size_t)((((colg & 31) >> 3) * 16 + (r & 15)) * 8) + (colg & 7);
          Cb[idx] = f2bf(v * bscale);
        } else {
          Cb[(size_t)r * N + colg] = f2bf(v * bscale);
        }
      }
    }
  }
}

// ---------------------------------------------------------------------------
// Column sums of X[8192 x 512]
// ---------------------------------------------------------------------------
__global__ __launch_bounds__(256) void colsum_kernel(const float* __restrict__ X,
                                                     float* __restrict__ cs) {
  const int tid = threadIdx.x;
  float s0 = 0.f, s1 = 0.f;
  const int r0 = blockIdx.x * 128;
  for (int r = r0; r < r0 + 128; ++r) {
    s0 += X[(size_t)r * DH + tid];
    s1 += X[(size_t)r * DH + tid + 256];
  }
  atomicAdd(&cs[tid], s0);
  atomicAdd(&cs[tid + 256], s1);
}

// x = (x + colmean) * 0.5 ; also emit bf16 copy
__global__ __launch_bounds__(256) void mix_kernel(float* __restrict__ X,
                                                  const float* __restrict__ cs,
                                                  unsigned short* __restrict__ Xb) {
  const size_t gid = (size_t)blockIdx.x * 256 + threadIdx.x;
  const int c4 = ((int)gid & 127) << 2;
  float4 x = *reinterpret_cast<float4*>(X + gid * 4);
  const float inv = 1.f / 8192.f;
  x.x = (x.x + cs[c4 + 0] * inv) * 0.5f;
  x.y = (x.y + cs[c4 + 1] * inv) * 0.5f;
  x.z = (x.z + cs[c4 + 2] * inv) * 0.5f;
  x.w = (x.w + cs[c4 + 3] * inv) * 0.5f;
  *reinterpret_cast<float4*>(X + gid * 4) = x;
  ushort4 o;
  o.x = f2bf(x.x); o.y = f2bf(x.y); o.z = f2bf(x.z); o.w = f2bf(x.w);
  *reinterpret_cast<ushort4*>(Xb + gid * 4) = o;
}

// ---------------------------------------------------------------------------
// MFMA scoring + streaming top-6, v4: v3 structure + coalesced packed-B loads.
// 256 blocks x 512 thr (8 waves). Block = 128 rows x 2048-col split.
// A (128x512) staged once in XOR-swizzled LDS; B from frag-packed ETp: each
// load is 64 lanes x 16B CONTIGUOUS (1KB/instr). kk==15 prefetches next jt's
// first B-frags so the dump/scan phase overlaps with loads in flight.
// ---------------------------------------------------------------------------
__global__ __launch_bounds__(512, 2) void score_topk_v3(
    const unsigned short* __restrict__ EHb, const unsigned short* __restrict__ ETp,
    float* __restrict__ tkv, int* __restrict__ tki) {
  __shared__ unsigned short sa[128 * 512];  // 131072 B, swizzled A
  __shared__ float swb[8][8 * 68];          // 17408 B, per-wave score slices
  const int tid = threadIdx.x;
  const int wave = tid >> 6, lane = tid & 63;
  const int lo16 = lane & 15, hi = lane >> 4;
  const int bid = blockIdx.x;
  const int split = (bid & 7) >> 1;
  const int rowblk = ((bid >> 3) << 1) | (bid & 1);
  const int grow0 = rowblk << 7;       // 128 rows/block
  const int colbase0 = split << 11;    // 2048 cols/split

  // stage A rows [grow0, grow0+128) swizzled
#pragma unroll
  for (int i = 0; i < 16; ++i) {
    const int c = i * 512 + tid;
    const int row = c >> 6, i8 = c & 63;
    const bf16x8 v = *reinterpret_cast<const bf16x8*>(
        EHb + (size_t)(grow0 + row) * DH + i8 * 8);
    const int byte = row * 1024 + ((i8 * 16) ^ ((row & 7) << 4));
    *reinterpret_cast<bf16x8*>(reinterpret_cast<char*>(sa) + byte) = v;
  }
  __syncthreads();

  float tv[2][6];
  int ti[2][6];
#pragma unroll
  for (int a = 0; a < 2; ++a)
#pragma unroll
    for (int s = 0; s < 6; ++s) { tv[a][s] = -3.4e38f; ti[a][s] = 0; }

  float* sw = swb[wave];

  // prologue: jt=0, kk=0 B-frags (coalesced from packed layout)
  bf16x8 bcur[4];
  {
    const int jg0 = (colbase0 + wave * 64) >> 4;
#pragma unroll
    for (int ct = 0; ct < 4; ++ct)
      bcur[ct] = *reinterpret_cast<const bf16x8*>(
          ETp + (size_t)(jg0 + ct) * 8192 + lane * 8);
  }

  for (int jt = 0; jt < 4; ++jt) {
    const int wcol0 = colbase0 + jt * 512 + wave * 64;
    const int jgbase = wcol0 >> 4;
    f32x4 acc[8][4];
#pragma unroll
    for (int rt = 0; rt < 8; ++rt)
#pragma unroll
      for (int ct = 0; ct < 4; ++ct) {
        acc[rt][ct].x = 0.f; acc[rt][ct].y = 0.f; acc[rt][ct].z = 0.f; acc[rt][ct].w = 0.f;
      }
#pragma unroll
    for (int kk = 0; kk < 16; ++kk) {
      bf16x8 bnxt[4];
      if (kk < 15) {
#pragma unroll
        for (int ct = 0; ct < 4; ++ct)
          bnxt[ct] = *reinterpret_cast<const bf16x8*>(
              ETp + (size_t)(jgbase + ct) * 8192 + (kk + 1) * 512 + lane * 8);
      } else {
        const int jtn = (jt == 3) ? 3 : (jt + 1);
        const int jgn = (colbase0 + jtn * 512 + wave * 64) >> 4;
#pragma unroll
        for (int ct = 0; ct < 4; ++ct)
          bnxt[ct] = *reinterpret_cast<const bf16x8*>(
              ETp + (size_t)(jgn + ct) * 8192 + lane * 8);
      }
      const int inner = (kk << 6) + (hi << 4);
#pragma unroll
      for (int rt = 0; rt < 8; ++rt) {
        const int row = rt * 16 + lo16;
        const bf16x8 af = *reinterpret_cast<const bf16x8*>(
            reinterpret_cast<const char*>(sa) + row * 1024 + (inner ^ ((row & 7) << 4)));
#pragma unroll
        for (int ct = 0; ct < 4; ++ct)
          acc[rt][ct] = __builtin_amdgcn_mfma_f32_16x16x32_bf16(af, bcur[ct], acc[rt][ct], 0, 0, 0);
      }
#pragma unroll
      for (int ct = 0; ct < 4; ++ct) bcur[ct] = bnxt[ct];
    }
    // dump/scan: 16 passes of (a row-half, ct, h col-half of frag)
#pragma unroll
    for (int a = 0; a < 2; ++a) {
#pragma unroll
      for (int ct = 0; ct < 4; ++ct) {
#pragma unroll
        for (int h = 0; h < 2; ++h) {
          if ((lo16 >> 3) == h) {
#pragma unroll
            for (int rtl = 0; rtl < 4; ++rtl)
              *reinterpret_cast<f32x4*>(sw + (lo16 & 7) * 68 + rtl * 16 + hi * 4) =
                  acc[a * 4 + rtl][ct];
          }
          asm volatile("s_waitcnt lgkmcnt(0)" ::: "memory");
#pragma unroll
          for (int cc = 0; cc < 8; ++cc) {
            const float v = sw[cc * 68 + lane];
            const int col = wcol0 + ct * 16 + h * 8 + cc;
            if (v > tv[a][5]) {
              tv[a][5] = v; ti[a][5] = col;
#pragma unroll
              for (int p = 5; p > 0; --p) {
                if (tv[a][p] > tv[a][p - 1]) {
                  float tvt = tv[a][p]; tv[a][p] = tv[a][p - 1]; tv[a][p - 1] = tvt;
                  int tit = ti[a][p]; ti[a][p] = ti[a][p - 1]; ti[a][p - 1] = tit;
                }
              }
            }
          }
          asm volatile("s_waitcnt lgkmcnt(0)" ::: "memory");
        }
      }
    }
  }
  __syncthreads();
  // merge: reuse A region. mv[128 rows][8 waves][6] + mi
  float* mv = reinterpret_cast<float*>(sa);
  int* mi = reinterpret_cast<int*>(mv + 128 * 8 * 6);
#pragma unroll
  for (int a = 0; a < 2; ++a) {
    const int row = a * 64 + lane;
#pragma unroll
    for (int s = 0; s < 6; ++s) {
      mv[(row * 8 + wave) * 6 + s] = tv[a][s];
      mi[(row * 8 + wave) * 6 + s] = ti[a][s];
    }
  }
  __syncthreads();
  if (tid < 128) {
    int pq[8] = {0, 0, 0, 0, 0, 0, 0, 0};
    const int base = (split * N_NODES + grow0 + tid) * 6;
    for (int s = 0; s < 6; ++s) {
      float best = -3.4e38f;
      int bi = 0x7fffffff, bq = 0;
#pragma unroll
      for (int q = 0; q < 8; ++q) {
        if (pq[q] < 6) {
          const float v = mv[(tid * 8 + q) * 6 + pq[q]];
          const int ix = mi[(tid * 8 + q) * 6 + pq[q]];
          if (v > best || (v == best && ix < bi)) { best = v; bi = ix; bq = q; }
        }
      }
      tkv[base + s] = best;
      tki[base + s] = bi;
#pragma unroll
      for (int q = 0; q < 8; ++q) pq[q] += (bq == q) ? 1 : 0;
    }
  }
}

// merge the 4 j-split top-6 lists into final top-6
__global__ __launch_bounds__(256) void merge_topk4(const float* __restrict__ tkv,
                                                   const int* __restrict__ tki,
                                                   float* __restrict__ fw,
                                                   int* __restrict__ fi) {
  const int n = blockIdx.x * 256 + threadIdx.x;
  int pq[NSPLIT] = {0, 0, 0, 0};
  for (int s = 0; s < 6; ++s) {
    float best = -3.4e38f;
    int bi = 0x7fffffff, bq = 0;
#pragma unroll
    for (int q = 0; q < NSPLIT; ++q) {
      if (pq[q] < 6) {
        const float v = tkv[((size_t)q * N_NODES + n) * 6 + pq[q]];
        const int ix = tki[((size_t)q * N_NODES + n) * 6 + pq[q]];
        if (v > best || (v == best && ix < bi)) { best = v; bi = ix; bq = q; }
      }
    }
    fw[n * 6 + s] = best;
    fi[n * 6 + s] = bi;
#pragma unroll
    for (int q = 0; q < NSPLIT; ++q) pq[q] += (bq == q) ? 1 : 0;
  }
}

// ---------------------------------------------------------------------------
// Per-node neighbor aggregation; outputs Ub, Vb in bf16.
// ---------------------------------------------------------------------------
__global__ __launch_bounds__(256) void agg_kernel(const float* __restrict__ EH,
                                                  const float* __restrict__ ET,
                                                  const float* __restrict__ fw,
                                                  const int* __restrict__ fi,
                                                  unsigned short* __restrict__ Ub,
                                                  unsigned short* __restrict__ Vb) {
  __shared__ float sNb[KNB][DH];
  __shared__ float sred[4][8];
  __shared__ float ska[8];
  const int node = blockIdx.x;
  const int tid = threadIdx.x;
  float w[KNB];
  int idx[KNB];
#pragma unroll
  for (int k = 0; k < KNB; ++k) {
    w[k] = fw[node * KNB + k];
    idx[k] = fi[node * KNB + k];
  }
  float mx = w[0];
#pragma unroll
  for (int k = 1; k < KNB; ++k) mx = fmaxf(mx, w[k]);
  float pk[KNB];
  float se = 0.f;
#pragma unroll
  for (int k = 0; k < KNB; ++k) { pk[k] = expf(w[k] - mx); se += pk[k]; }
  const float inv_se = 1.f / se;
#pragma unroll
  for (int k = 0; k < KNB; ++k) pk[k] *= inv_se;
  for (int e = tid; e < KNB * DH; e += 256) {
    int k = e >> 9, d = e & 511;
    sNb[k][d] = ET[(size_t)idx[k] * DH + d];
  }
  __syncthreads();
  float eh[2];
  eh[0] = EH[(size_t)node * DH + tid];
  eh[1] = EH[(size_t)node * DH + tid + 256];
  float ka[KNB] = {0, 0, 0, 0, 0, 0};
#pragma unroll
  for (int t = 0; t < 2; ++t) {
    const int d = tid + t * 256;
    const float e_ = eh[t];
#pragma unroll
    for (int k = 0; k < KNB; ++k) {
      float Nb = sNb[k][d];
      float ehr = pk[k] * Nb + (1.f - pk[k]) * e_;
      float g = tanhf(e_ + ehr);
      ka[k] = fmaf(Nb, g, ka[k]);
    }
  }
#pragma unroll
  for (int k = 0; k < KNB; ++k) {
    float v = ka[k];
#pragma unroll
    for (int off = 32; off > 0; off >>= 1) v += __shfl_down(v, off, 64);
    if ((tid & 63) == 0) sred[tid >> 6][k] = v;
  }
  __syncthreads();
  if (tid < KNB) ska[tid] = sred[0][tid] + sred[1][tid] + sred[2][tid] + sred[3][tid];
  __syncthreads();
  float kav[KNB];
#pragma unroll
  for (int k = 0; k < KNB; ++k) kav[k] = ska[k];
  float kmx = kav[0];
#pragma unroll
  for (int k = 1; k < KNB; ++k) kmx = fmaxf(kmx, kav[k]);
  float kp[KNB];
  float ks = 0.f;
#pragma unroll
  for (int k = 0; k < KNB; ++k) { kp[k] = expf(kav[k] - kmx); ks += kp[k]; }
  const float inv_ks = 1.f / ks;
#pragma unroll
  for (int k = 0; k < KNB; ++k) kp[k] *= inv_ks;
#pragma unroll
  for (int t = 0; t < 2; ++t) {
    const int d = tid + t * 256;
    float eNh = 0.f;
#pragma unroll
    for (int k = 0; k < KNB; ++k) eNh = fmaf(kp[k], sNb[k][d], eNh);
    const float e_ = eh[t];
    Ub[(size_t)node * DH + d] = f2bf(e_ + eNh);
    Vb[(size_t)node * DH + d] = f2bf(e_ * eNh);
  }
}

// a[n] = dot(hid_bf16[n], att2_w) + att2_b ; one wave per node
__global__ __launch_bounds__(256) void att_dot(const unsigned short* __restrict__ HIDb,
                                               const float* __restrict__ w2,
                                               const float* __restrict__ b2,
                                               float* __restrict__ a) {
  const int wid = threadIdx.x >> 6, lane = threadIdx.x & 63;
  const int node = blockIdx.x * 4 + wid;
  const ushort4 h4 = *reinterpret_cast<const ushort4*>(HIDb + (size_t)node * 256 + lane * 4);
  const float4 w4 = *reinterpret_cast<const float4*>(w2 + lane * 4);
  float s = bf2f(h4.x) * w4.x + bf2f(h4.y) * w4.y + bf2f(h4.z) * w4.z + bf2f(h4.w) * w4.w;
#pragma unroll
  for (int off = 32; off > 0; off >>= 1) s += __shfl_down(s, off, 64);
  if (lane == 0) a[node] = s + b2[0];
}

// global softmax stats over a[8192]
__global__ __launch_bounds__(1024) void softmax_stats(const float* __restrict__ a,
                                                      float* __restrict__ st) {
  __shared__ float red[16];
  __shared__ float bc;
  const int tid = threadIdx.x;
  float mx = -3.4e38f;
  for (int i = tid; i < N_NODES; i += 1024) mx = fmaxf(mx, a[i]);
#pragma unroll
  for (int off = 32; off > 0; off >>= 1) mx = fmaxf(mx, __shfl_xor(mx, off, 64));
  if ((tid & 63) == 0) red[tid >> 6] = mx;
  __syncthreads();
  if (tid == 0) {
    float m = red[0];
    for (int i = 1; i < 16; ++i) m = fmaxf(m, red[i]);
    bc = m;
  }
  __syncthreads();
  const float gm = bc;
  float se = 0.f;
  for (int i = tid; i < N_NODES; i += 1024) se += expf(a[i] - gm);
#pragma unroll
  for (int off = 32; off > 0; off >>= 1) se += __shfl_xor(se, off, 64);
  if ((tid & 63) == 0) red[tid >> 6] = se;
  __syncthreads();
  if (tid == 0) {
    float s = 0.f;
    for (int i = 0; i < 16; ++i) s += red[i];
    st[0] = gm;
    st[1] = s;
  }
}

// h[c] = sum_n softmax(a)_n * emb_bf16[n][c]
__global__ __launch_bounds__(256) void readout(const unsigned short* __restrict__ EMBb,
                                               const float* __restrict__ a,
                                               const float* __restrict__ st,
                                               float* __restrict__ h) {
  __shared__ float sacc[4][64];
  const int tid = threadIdx.x;
  const int c = (blockIdx.x << 6) + (tid & 63);
  const int rsub = tid >> 6;
  const float mx = st[0], inv_se = 1.f / st[1];
  const int r0 = blockIdx.y << 8;
  float acc = 0.f;
  for (int i = 0; i < 64; ++i) {
    const int r = r0 + (i << 2) + rsub;
    const float g = expf(a[r] - mx);
    acc = fmaf(g, bf2f(EMBb[(size_t)r * DH + c]), acc);
  }
  sacc[rsub][tid & 63] = acc * inv_se;
  __syncthreads();
  if (rsub == 0) {
    float t = sacc[0][tid] + sacc[1][tid] + sacc[2][tid] + sacc[3][tid];
    atomicAdd(&h[c], t);
  }
}

// layernorm + final fc -> 2 logits
__global__ __launch_bounds__(512) void finalize(const float* __restrict__ h,
                                                const float* __restrict__ ln_g,
                                                const float* __restrict__ ln_b,
                                                const float* __restrict__ fc_w,
                                                const float* __restrict__ fc_b,
                                                float* __restrict__ out) {
  __shared__ float red0[8];
  __shared__ float red1[8];
  __shared__ float bc[2];
  const int tid = threadIdx.x;
  const int wid = tid >> 6, lane = tid & 63;
  const float v = h[tid];
  float s = v;
#pragma unroll
  for (int off = 32; off > 0; off >>= 1) s += __shfl_xor(s, off, 64);
  if (lane == 0) red0[wid] = s;
  __syncthreads();
  if (tid == 0) {
    float t = 0.f;
    for (int i = 0; i < 8; ++i) t += red0[i];
    bc[0] = t * (1.f / 512.f);
  }
  __syncthreads();
  const float mu = bc[0];
  const float dv = v - mu;
  s = dv * dv;
#pragma unroll
  for (int off = 32; off > 0; off >>= 1) s += __shfl_xor(s, off, 64);
  if (lane == 0) red0[wid] = s;
  __syncthreads();
  if (tid == 0) {
    float t = 0.f;
    for (int i = 0; i < 8; ++i) t += red0[i];
    bc[1] = t * (1.f / 512.f);
  }
  __syncthreads();
  const float var = bc[1];
  const float hn = dv / sqrtf(var + 1e-5f) * ln_g[tid] + ln_b[tid];
  float l0 = hn * fc_w[tid * 2 + 0];
  float l1 = hn * fc_w[tid * 2 + 1];
#pragma unroll
  for (int off = 32; off > 0; off >>= 1) {
    l0 += __shfl_xor(l0, off, 64);
    l1 += __shfl_xor(l1, off, 64);
  }
  if (lane == 0) { red0[wid] = l0; red1[wid] = l1; }
  __syncthreads();
  if (tid == 0) {
    float t0 = 0.f, t1 = 0.f;
    for (int i = 0; i < 8; ++i) { t0 += red0[i]; t1 += red1[i]; }
    out[0] = t0 + fc_b[0];
    out[1] = t1 + fc_b[1];
  }
}

// ---------------------------------------------------------------------------
extern "C" void kernel_launch(void* const* d_in, const int* in_sizes, int n_in,
                              void* d_out, int out_size, void* d_ws, size_t ws_size,
                              hipStream_t stream) {
  const float* x_s    = (const float*)d_in[0];
  const float* fc1_w  = (const float*)d_in[1];
  const float* fc1_b  = (const float*)d_in[2];
  const float* wh_w   = (const float*)d_in[3];
  const float* wh_b   = (const float*)d_in[4];
  const float* wt_w   = (const float*)d_in[5];
  const float* wt_b   = (const float*)d_in[6];
  const float* l1_w   = (const float*)d_in[7];
  const float* l1_b   = (const float*)d_in[8];
  const float* l2_w   = (const float*)d_in[9];
  const float* l2_b   = (const float*)d_in[10];
  const float* att1_w = (const float*)d_in[11];
  const float* att1_b = (const float*)d_in[12];
  const float* att2_w = (const float*)d_in[13];
  const float* att2_b = (const float*)d_in[14];
  const float* ln_g   = (const float*)d_in[15];
  const float* ln_b   = (const float*)d_in[16];
  const float* fc_w   = (const float*)d_in[17];
  const float* fc_b   = (const float*)d_in[18];

  float* ws = (float*)d_ws;
  const size_t BIG = (size_t)N_NODES * DH;  // 4,194,304
  float* B1 = ws;
  float* B2 = ws + BIG;
  unsigned short* R1 = (unsigned short*)(ws + 2 * BIG);  // xsb -> EHb -> Ub -> hidb
  unsigned short* R2 = R1 + BIG;                          // xb -> Vb
  unsigned short* R3 = R2 + BIG;                          // ETp (packed) -> embb
  unsigned short* WT = R3 + BIG;                          // transposed bf16 weights
  float* tail = (float*)(WT + 1376256);
  float* tkv    = tail;                          // 4*8192*6
  int*   tki    = (int*)(tkv + NSPLIT * N_NODES * 6);
  float* fwv    = (float*)(tki + NSPLIT * N_NODES * 6);
  int*   fiv    = (int*)(fwv + N_NODES * 6);
  float* colsum = (float*)(fiv + N_NODES * 6);
  float* av     = colsum + DH;
  float* stats  = av + N_NODES;
  float* hbuf   = stats + 16;

  unsigned short* fc1t  = WT + 0;
  unsigned short* wht   = WT + 196608;
  unsigned short* wtt   = WT + 458752;
  unsigned short* l1t   = WT + 720896;
  unsigned short* l2t   = WT + 983040;
  unsigned short* att1t = WT + 1245184;

  const float kscale = 0.044194173824159216f;  // 512^-0.5

  // 0. prep
  prep_weights<<<5376, 256, 0, stream>>>(fc1_w, wh_w, wt_w, l1_w, l2_w, att1_w, WT);
  convert_xs<<<3072, 256, 0, stream>>>(x_s, R1);
  // 1. x = lrelu(xsb @ fc1t^T + b) -> B1
  gemm_bf16<1, 0, 1, 0, 0><<<dim3(8, 128), 256, 0, stream>>>(
      R1, fc1t, fc1_b, B1, nullptr, 1.f, N_NODES, DIN, DH);
  // 2. mean-mix -> B1 fp32 + xb bf16 (R2)
  hipMemsetAsync(colsum, 0, DH * sizeof(float), stream);
  colsum_kernel<<<64, 256, 0, stream>>>(B1, colsum);
  mix_kernel<<<4096, 256, 0, stream>>>(B1, colsum, R2);
  // 3. e_h -> B1 + EHb*scale (R1, row-major); e_t -> B2 + ETp (R3, frag-packed)
  gemm_bf16<0, 0, 1, 1, 0><<<dim3(8, 128), 256, 0, stream>>>(
      R2, wht, wh_b, B1, R1, kscale, N_NODES, DH, DH);
  gemm_bf16<0, 0, 1, 1, 1><<<dim3(8, 128), 256, 0, stream>>>(
      R2, wtt, wt_b, B2, R3, 1.f, N_NODES, DH, DH);
  // 4. scoring v4 (coalesced packed B) + merge
  score_topk_v3<<<256, 512, 0, stream>>>(R1, R3, tkv, tki);
  merge_topk4<<<32, 256, 0, stream>>>(tkv, tki, fwv, fiv);
  // 5. aggregation -> Ub (R1), Vb (R2)
  agg_kernel<<<N_NODES, 256, 0, stream>>>(B1, B2, fwv, fiv, R1, R2);
  // 6. emb = lrelu(Ub@l1+b1) + lrelu(Vb@l2+b2) -> B1 fp32, embb (R3)
  gemm_bf16<1, 0, 1, 0, 0><<<dim3(8, 128), 256, 0, stream>>>(
      R1, l1t, l1_b, B1, nullptr, 1.f, N_NODES, DH, DH);
  gemm_bf16<1, 1, 0, 1, 0><<<dim3(8, 128), 256, 0, stream>>>(
      R2, l2t, l2_b, B1, R3, 1.f, N_NODES, DH, DH);
  // 7. attention readout
  gemm_bf16<1, 0, 0, 1, 0><<<dim3(4, 128), 256, 0, stream>>>(
      R3, att1t, att1_b, B2, R1, 1.f, N_NODES, DH, 256);
  att_dot<<<2048, 256, 0, stream>>>(R1, att2_w, att2_b, av);
  softmax_stats<<<1, 1024, 0, stream>>>(av, stats);
  hipMemsetAsync(hbuf, 0, DH * sizeof(float), stream);
  readout<<<dim3(8, 32), 256, 0, stream>>>(R3, av, stats, hbuf);
  // 8. layernorm + logits
  finalize<<<1, 512, 0, stream>>>(hbuf, ln_g, ln_b, fc_w, fc_b, (float*)d_out);
}